// Round 1
// baseline (1834.289 us; speedup 1.0000x reference)
//
#include <hip/hip_runtime.h>
#include <math.h>

#define SLOPE 0.01

// ---------------------------------------------------------------------------
// Graph: N=38333 nodes, E=N*32 edges. All math in fp64 for accuracy; the
// absmax threshold (6.96e-07 on outputs of max ~3.5e-05) demands better than
// casual f32 accumulation over 1.2M-edge segment sums and 38k-term dots.
// ---------------------------------------------------------------------------

static inline int cdiv_l(long a, int b) { return (int)((a + (long)b - 1) / (long)b); }

__global__ void k_deg(const int* __restrict__ col, float* __restrict__ degf, int E) {
    int e = blockIdx.x * blockDim.x + threadIdx.x;
    if (e < E) atomicAdd(degf + col[e], 1.0f);   // integer counts, exact in f32
}

__global__ void k_dinv(const float* __restrict__ degf, double* __restrict__ dinv, int N) {
    int i = blockIdx.x * blockDim.x + threadIdx.x;
    if (i < N) dinv[i] = 1.0 / sqrt((double)degf[i] + 1.0);
}

// h0[i] = [emb[id0(i)] (62) | emb[id1(i)] (62) | x[i,2:5] (3)]  -> N x 127
__global__ void k_h0(const float* __restrict__ x, const float* __restrict__ emb,
                     double* __restrict__ h0, int N) {
    long idx = (long)blockIdx.x * blockDim.x + threadIdx.x;
    long total = (long)N * 127;
    if (idx >= total) return;
    int i = (int)(idx / 127);
    int k = (int)(idx % 127);
    const float* xr = x + (long)i * 5;
    double v;
    if (k < 62) {
        int id0 = (int)xr[0];
        v = (double)emb[(long)id0 * 62 + k];
    } else if (k < 124) {
        int id1 = (int)xr[1];
        v = (double)emb[(long)id1 * 62 + (k - 62)];
    } else {
        v = (double)xr[2 + (k - 124)];
    }
    h0[idx] = v;
}

// hw[i,o] = sum_k h[i,k] * W[k,o]   (h: stride ld, W: Din x Dout row-major f32)
__global__ void k_hw(const double* __restrict__ h, int ld, const float* __restrict__ W,
                     int Din, int Dout, double* __restrict__ hw, int N) {
    long idx = (long)blockIdx.x * blockDim.x + threadIdx.x;
    long total = (long)N * Dout;
    if (idx >= total) return;
    int i = (int)(idx / Dout);
    int o = (int)(idx % Dout);
    const double* hr = h + (long)i * ld;
    double acc = 0.0;
    for (int k = 0; k < Din; ++k)
        acc += hr[k] * (double)W[(long)k * Dout + o];
    hw[(long)i * Dout + o] = acc;
}

// agg[col[e], o] += hw[row[e], o] * dinv[row]*dinv[col]
__global__ void k_edge(const int* __restrict__ row, const int* __restrict__ col,
                       const double* __restrict__ dinv, const double* __restrict__ hw,
                       double* __restrict__ agg, int Dout, long total) {
    long idx = (long)blockIdx.x * blockDim.x + threadIdx.x;
    if (idx >= total) return;
    int e = (int)(idx / Dout);
    int o = (int)(idx % Dout);
    int r = row[e], c = col[e];
    double nrm = dinv[r] * dinv[c];
    atomicAdd(&agg[(long)c * Dout + o], hw[(long)r * Dout + o] * nrm);
}

// out[i,o] = act( agg + hw*dinv[i]^2 + b[o] ); mode 0: lrelu, mode 1: lrelu(t)+t
__global__ void k_combine(const double* __restrict__ hw, const double* __restrict__ agg,
                          const double* __restrict__ dinv, const float* __restrict__ b,
                          double* __restrict__ out, int Dout, int N, int mode) {
    long idx = (long)blockIdx.x * blockDim.x + threadIdx.x;
    long total = (long)N * Dout;
    if (idx >= total) return;
    int i = (int)(idx / Dout);
    int o = (int)(idx % Dout);
    double sn = dinv[i] * dinv[i];
    double t = agg[idx] + hw[idx] * sn + (double)b[o];
    double r;
    if (mode == 0) r = (t >= 0.0) ? t : SLOPE * t;
    else           r = (t >= 0.0) ? 2.0 * t : (SLOPE * t + t);
    out[idx] = r;
}

// o1[j] = relu( sum_i v[i]*Wf1[i,j] + bf1[j] ),  j = blockIdx.x in [0,128)
__global__ void k_fc1(const double* __restrict__ v, const float* __restrict__ Wf1,
                      const float* __restrict__ bf1, double* __restrict__ o1, int N) {
    int j = blockIdx.x;
    double acc = 0.0;
    for (int i = threadIdx.x; i < N; i += blockDim.x)
        acc += v[i] * (double)Wf1[(long)i * 128 + j];
    __shared__ double red[256];
    red[threadIdx.x] = acc;
    __syncthreads();
    for (int s = 128; s > 0; s >>= 1) {
        if (threadIdx.x < s) red[threadIdx.x] += red[threadIdx.x + s];
        __syncthreads();
    }
    if (threadIdx.x == 0) {
        double t = red[0] + (double)bf1[j];
        o1[j] = (t > 0.0) ? t : 0.0;
    }
}

// out[j] = relu( sum_k o1[k]*Wf2[k,j] + bf2[j] ), one block of 128 threads
__global__ void k_fc2(const double* __restrict__ o1, const float* __restrict__ Wf2,
                      const float* __restrict__ bf2, float* __restrict__ out) {
    int j = threadIdx.x;
    double acc = 0.0;
    for (int k = 0; k < 128; ++k)
        acc += o1[k] * (double)Wf2[(long)k * 128 + j];
    double t = acc + (double)bf2[j];
    out[j] = (float)((t > 0.0) ? t : 0.0);
}

static void run_gcn(const double* hin, int ld, const float* W, const float* b,
                    int Din, int Dout, int mode,
                    const int* row, const int* col, const double* dinv,
                    double* HW, double* AGG, double* hout,
                    int N, int E, hipStream_t stream) {
    k_hw<<<cdiv_l((long)N * Dout, 256), 256, 0, stream>>>(hin, ld, W, Din, Dout, HW, N);
    hipMemsetAsync(AGG, 0, (size_t)N * Dout * sizeof(double), stream);
    long tot = (long)E * Dout;
    k_edge<<<cdiv_l(tot, 256), 256, 0, stream>>>(row, col, dinv, HW, AGG, Dout, tot);
    k_combine<<<cdiv_l((long)N * Dout, 256), 256, 0, stream>>>(HW, AGG, dinv, b, hout, Dout, N, mode);
}

extern "C" void kernel_launch(void* const* d_in, const int* in_sizes, int n_in,
                              void* d_out, int out_size, void* d_ws, size_t ws_size,
                              hipStream_t stream) {
    const float* x   = (const float*)d_in[0];
    const int*   ei  = (const int*)d_in[1];
    const float* emb = (const float*)d_in[2];
    const float* W1  = (const float*)d_in[3];
    const float* b1  = (const float*)d_in[4];
    const float* W2  = (const float*)d_in[5];
    const float* b2  = (const float*)d_in[6];
    const float* W3  = (const float*)d_in[7];
    const float* b3  = (const float*)d_in[8];
    const float* W4  = (const float*)d_in[9];
    const float* b4  = (const float*)d_in[10];
    const float* W5  = (const float*)d_in[11];
    const float* b5  = (const float*)d_in[12];
    const float* Wf1 = (const float*)d_in[13];
    const float* bf1 = (const float*)d_in[14];
    const float* Wf2 = (const float*)d_in[15];
    const float* bf2 = (const float*)d_in[16];

    const int N = in_sizes[0] / 5;
    const int E = in_sizes[1] / 2;
    const int* row = ei;       // edge_index[0]
    const int* col = ei + E;   // edge_index[1]

    // --- workspace carving (all zeroed/overwritten each call; ws is poisoned) ---
    char* ws = (char*)d_ws;
    size_t off = 0;
    auto alloc = [&](size_t bytes) -> void* {
        void* p = ws + off;
        off += (bytes + 255) & ~(size_t)255;
        return p;
    };
    double* dinv = (double*)alloc((size_t)N * sizeof(double));
    double* H0   = (double*)alloc((size_t)N * 127 * sizeof(double)); // h0; reused for h2,h4
    double* HW   = (double*)alloc((size_t)N * 64 * sizeof(double));
    double* AGG  = (double*)alloc((size_t)N * 64 * sizeof(double));
    double* HB   = (double*)alloc((size_t)N * 64 * sizeof(double)); // h1; reused for h3
    double* V    = (double*)alloc((size_t)N * sizeof(double));
    double* O1   = (double*)alloc(128 * sizeof(double));
    float*  degf = (float*)alloc((size_t)N * sizeof(float));

    // --- degree / dinv ---
    hipMemsetAsync(degf, 0, (size_t)N * sizeof(float), stream);
    k_deg<<<cdiv_l(E, 256), 256, 0, stream>>>(col, degf, E);
    k_dinv<<<cdiv_l(N, 256), 256, 0, stream>>>(degf, dinv, N);

    // --- input features ---
    k_h0<<<cdiv_l((long)N * 127, 256), 256, 0, stream>>>(x, emb, H0, N);

    // --- 5 GCN layers ---
    // L1: h0(127)->h1(64), lrelu
    run_gcn(H0, 127, W1, b1, 127, 64, 0, row, col, dinv, HW, AGG, HB, N, E, stream);
    // L2: h1(64)->h2(32), lrelu     (h2 into H0 region)
    run_gcn(HB, 64, W2, b2, 64, 32, 0, row, col, dinv, HW, AGG, H0, N, E, stream);
    // L3: h2(32)->h3(32), lrelu(t)+t (h3 into HB region)
    run_gcn(H0, 32, W3, b3, 32, 32, 1, row, col, dinv, HW, AGG, HB, N, E, stream);
    // L4: h3(32)->h4(32), lrelu(t)+t (h4 into H0 region)
    run_gcn(HB, 32, W4, b4, 32, 32, 1, row, col, dinv, HW, AGG, H0, N, E, stream);
    // L5: h4(32)->v(1), lrelu
    run_gcn(H0, 32, W5, b5, 32, 1, 0, row, col, dinv, HW, AGG, V, N, E, stream);

    // --- FC head ---
    k_fc1<<<128, 256, 0, stream>>>(V, Wf1, bf1, O1, N);
    k_fc2<<<1, 128, 0, stream>>>(O1, Wf2, bf2, (float*)d_out);
}

// Round 2
// 1026.367 us; speedup vs baseline: 1.7872x; 1.7872x over previous
//
#include <hip/hip_runtime.h>
#include <math.h>

#define SLOPE 0.01

// ---------------------------------------------------------------------------
// f32 storage + f64 register accumulation. CSR gather instead of atomic
// scatter: round-1 profile showed k_edge atomics writing 613 MB to HBM per
// layer (agg is only 19.6 MB) -- scatter atomics defeat the cache entirely.
// Error budget: f32 storage rounding ~6e-8 rel/layer => ~1e-10 abs at the
// 3.5e-5 output scale, vs 7e-7 threshold.
// ---------------------------------------------------------------------------

static inline int cdiv_l(long a, int b) { return (int)((a + (long)b - 1) / (long)b); }

// ---------------- CSR build ----------------
__global__ void k_count(const int* __restrict__ col, int* __restrict__ cnt, int E) {
    int e = blockIdx.x * blockDim.x + threadIdx.x;
    if (e < E) atomicAdd(cnt + col[e], 1);
}

// single-block exclusive scan over cnt[N] -> off[N+1]; also seeds cursor[]
__global__ void k_scan(const int* __restrict__ cnt, int* __restrict__ off,
                       int* __restrict__ cursor, int N) {
    __shared__ int sums[1024];
    int t = threadIdx.x;
    int chunk = (N + 1023) / 1024;
    int start = t * chunk, end = min(start + chunk, N);
    int s = 0;
    for (int i = start; i < end; ++i) s += cnt[i];
    sums[t] = s;
    __syncthreads();
    for (int d = 1; d < 1024; d <<= 1) {
        int v = (t >= d) ? sums[t - d] : 0;
        __syncthreads();
        sums[t] += v;
        __syncthreads();
    }
    int pre = (t == 0) ? 0 : sums[t - 1];
    for (int i = start; i < end; ++i) {
        off[i] = pre; cursor[i] = pre; pre += cnt[i];
    }
    if (t == 1023) off[N] = sums[1023];   // == E
}

__global__ void k_fill(const int* __restrict__ row, const int* __restrict__ col,
                       int* __restrict__ cursor, int* __restrict__ srcs, int E) {
    int e = blockIdx.x * blockDim.x + threadIdx.x;
    if (e >= E) return;
    int pos = atomicAdd(cursor + col[e], 1);
    srcs[pos] = row[e];
}

__global__ void k_dinv(const int* __restrict__ cnt, float* __restrict__ dinv, int N) {
    int i = blockIdx.x * blockDim.x + threadIdx.x;
    if (i < N) dinv[i] = (float)(1.0 / sqrt((double)cnt[i] + 1.0));
}

// ---------------- features ----------------
// h0[i] = [emb[id0(i)] (62) | emb[id1(i)] (62) | x[i,2:5] (3)]  -> N x 127 (f32)
__global__ void k_h0(const float* __restrict__ x, const float* __restrict__ emb,
                     float* __restrict__ h0, int N) {
    int idx = blockIdx.x * blockDim.x + threadIdx.x;
    long total = (long)N * 127;
    if (idx >= total) return;
    int i = idx / 127;
    int k = idx % 127;
    const float* xr = x + (long)i * 5;
    float v;
    if (k < 62) {
        int id0 = (int)xr[0];
        v = emb[(long)id0 * 62 + k];
    } else if (k < 124) {
        int id1 = (int)xr[1];
        v = emb[(long)id1 * 62 + (k - 62)];
    } else {
        v = xr[2 + (k - 124)];
    }
    h0[idx] = v;
}

// ---------------- dense hw = h @ W ----------------
__global__ void k_hw(const float* __restrict__ h, int ld, const float* __restrict__ W,
                     int Din, int Dout, float* __restrict__ hw, int N) {
    int idx = blockIdx.x * blockDim.x + threadIdx.x;
    long total = (long)N * Dout;
    if (idx >= total) return;
    int i = idx / Dout;
    int o = idx % Dout;
    const float* hr = h + (long)i * ld;
    double acc = 0.0;
    for (int k = 0; k < Din; ++k)
        acc += (double)hr[k] * (double)W[(long)k * Dout + o];
    hw[idx] = (float)acc;
}

// ---------------- fused gather + self + bias + activation ----------------
// out[c,o] = act( dinv[c] * ( sum_{e in in(c)} hw[src,o]*dinv[src]
//                             + hw[c,o]*dinv[c] ) + b[o] )
template<int DOUT>
__global__ void k_gather(const int* __restrict__ off, const int* __restrict__ srcs,
                         const float* __restrict__ dinv, const float* __restrict__ hw,
                         const float* __restrict__ b, float* __restrict__ out,
                         int N, int mode) {
    int idx = blockIdx.x * blockDim.x + threadIdx.x;
    if (idx >= N * DOUT) return;
    int c = idx / DOUT;
    int o = idx % DOUT;
    int e0 = off[c], e1 = off[c + 1];
    double dc = (double)dinv[c];
    double acc = (double)hw[(long)c * DOUT + o] * dc;  // self-loop term
    for (int e = e0; e < e1; ++e) {
        int r = srcs[e];
        acc += (double)hw[(long)r * DOUT + o] * (double)dinv[r];
    }
    double t = acc * dc + (double)b[o];
    double res;
    if (mode == 0) res = (t >= 0.0) ? t : SLOPE * t;
    else           res = (t >= 0.0) ? 2.0 * t : (1.0 + SLOPE) * t;
    out[idx] = (float)res;
}

// ---------------- FC head ----------------
// partial[bl, j] = sum_{i in chunk(bl)} v[i] * Wf1[i, j]
__global__ void k_fc1a(const float* __restrict__ v, const float* __restrict__ Wf1,
                       double* __restrict__ part, int N, int chunk) {
    int j = threadIdx.x;            // 0..127
    int bl = blockIdx.x;            // 0..63
    int i0 = bl * chunk, i1 = min(i0 + chunk, N);
    double acc = 0.0;
    for (int i = i0; i < i1; ++i)
        acc += (double)v[i] * (double)Wf1[(long)i * 128 + j];
    part[bl * 128 + j] = acc;
}

__global__ void k_fc1b(const double* __restrict__ part, const float* __restrict__ bf1,
                       double* __restrict__ o1) {
    int j = threadIdx.x;
    double acc = 0.0;
    for (int bl = 0; bl < 64; ++bl) acc += part[bl * 128 + j];
    double t = acc + (double)bf1[j];
    o1[j] = (t > 0.0) ? t : 0.0;
}

__global__ void k_fc2(const double* __restrict__ o1, const float* __restrict__ Wf2,
                      const float* __restrict__ bf2, float* __restrict__ out) {
    int j = threadIdx.x;
    double acc = 0.0;
    for (int k = 0; k < 128; ++k)
        acc += o1[k] * (double)Wf2[(long)k * 128 + j];
    double t = acc + (double)bf2[j];
    out[j] = (float)((t > 0.0) ? t : 0.0);
}

// ---------------- layer driver ----------------
template<int DOUT>
static void run_gcn(const float* hin, int ld, const float* W, const float* b,
                    int Din, int mode,
                    const int* off, const int* srcs, const float* dinv,
                    float* HW, float* hout, int N, hipStream_t stream) {
    k_hw<<<cdiv_l((long)N * DOUT, 256), 256, 0, stream>>>(hin, ld, W, Din, DOUT, HW, N);
    k_gather<DOUT><<<cdiv_l((long)N * DOUT, 256), 256, 0, stream>>>(
        off, srcs, dinv, HW, b, hout, N, mode);
}

extern "C" void kernel_launch(void* const* d_in, const int* in_sizes, int n_in,
                              void* d_out, int out_size, void* d_ws, size_t ws_size,
                              hipStream_t stream) {
    const float* x   = (const float*)d_in[0];
    const int*   ei  = (const int*)d_in[1];
    const float* emb = (const float*)d_in[2];
    const float* W1  = (const float*)d_in[3];
    const float* b1  = (const float*)d_in[4];
    const float* W2  = (const float*)d_in[5];
    const float* b2  = (const float*)d_in[6];
    const float* W3  = (const float*)d_in[7];
    const float* b3  = (const float*)d_in[8];
    const float* W4  = (const float*)d_in[9];
    const float* b4  = (const float*)d_in[10];
    const float* W5  = (const float*)d_in[11];
    const float* b5  = (const float*)d_in[12];
    const float* Wf1 = (const float*)d_in[13];
    const float* bf1 = (const float*)d_in[14];
    const float* Wf2 = (const float*)d_in[15];
    const float* bf2 = (const float*)d_in[16];

    const int N = in_sizes[0] / 5;
    const int E = in_sizes[1] / 2;
    const int* row = ei;       // edge_index[0]
    const int* col = ei + E;   // edge_index[1]

    // --- workspace carving ---
    char* ws = (char*)d_ws;
    size_t off_b = 0;
    auto alloc = [&](size_t bytes) -> void* {
        void* p = ws + off_b;
        off_b += (bytes + 255) & ~(size_t)255;
        return p;
    };
    int*   cnt    = (int*)alloc((size_t)N * sizeof(int));
    int*   offcsr = (int*)alloc((size_t)(N + 1) * sizeof(int));
    int*   cursor = (int*)alloc((size_t)N * sizeof(int));
    int*   srcs   = (int*)alloc((size_t)E * sizeof(int));
    float* dinv   = (float*)alloc((size_t)N * sizeof(float));
    float* H0     = (float*)alloc((size_t)N * 127 * sizeof(float)); // h0; reused h2,h4
    float* HW     = (float*)alloc((size_t)N * 64 * sizeof(float));
    float* HB     = (float*)alloc((size_t)N * 64 * sizeof(float));  // h1; reused h3
    float* V      = (float*)alloc((size_t)N * sizeof(float));
    double* part  = (double*)alloc(64 * 128 * sizeof(double));
    double* O1    = (double*)alloc(128 * sizeof(double));

    // --- CSR build + dinv ---
    hipMemsetAsync(cnt, 0, (size_t)N * sizeof(int), stream);
    k_count<<<cdiv_l(E, 256), 256, 0, stream>>>(col, cnt, E);
    k_scan<<<1, 1024, 0, stream>>>(cnt, offcsr, cursor, N);
    k_fill<<<cdiv_l(E, 256), 256, 0, stream>>>(row, col, cursor, srcs, E);
    k_dinv<<<cdiv_l(N, 256), 256, 0, stream>>>(cnt, dinv, N);

    // --- input features ---
    k_h0<<<cdiv_l((long)N * 127, 256), 256, 0, stream>>>(x, emb, H0, N);

    // --- 5 GCN layers ---
    run_gcn<64>(H0, 127, W1, b1, 127, 0, offcsr, srcs, dinv, HW, HB, N, stream);
    run_gcn<32>(HB,  64, W2, b2,  64, 0, offcsr, srcs, dinv, HW, H0, N, stream);
    run_gcn<32>(H0,  32, W3, b3,  32, 1, offcsr, srcs, dinv, HW, HB, N, stream);
    run_gcn<32>(HB,  32, W4, b4,  32, 1, offcsr, srcs, dinv, HW, H0, N, stream);
    run_gcn<1> (H0,  32, W5, b5,  32, 0, offcsr, srcs, dinv, HW, V,  N, stream);

    // --- FC head ---
    int chunk = (N + 63) / 64;
    k_fc1a<<<64, 128, 0, stream>>>(V, Wf1, part, N, chunk);
    k_fc1b<<<1, 128, 0, stream>>>(part, bf1, O1);
    k_fc2<<<1, 128, 0, stream>>>(O1, Wf2, bf2, (float*)d_out);
}

// Round 3
// 841.760 us; speedup vs baseline: 2.1791x; 1.2193x over previous
//
#include <hip/hip_runtime.h>
#include <math.h>

#define SLOPE 0.01
#define FC1_BLOCKS 512

// ---------------------------------------------------------------------------
// f32 storage + f64 register accumulation. CSR gather (round 1: atomics wrote
// 613 MB/layer). Round 2: k_fc1a was latency-bound at 64 blocks (1.2% occ,
// 230 us for a 19.6 MB stream) -> 512 blocks + 4-way ILP accumulators.
// ---------------------------------------------------------------------------

static inline int cdiv_l(long a, int b) { return (int)((a + (long)b - 1) / (long)b); }

// ---------------- CSR build ----------------
__global__ void k_count(const int* __restrict__ col, int* __restrict__ cnt, int E) {
    int e = blockIdx.x * blockDim.x + threadIdx.x;
    if (e < E) atomicAdd(cnt + col[e], 1);
}

// single-block exclusive scan over cnt[N] -> off[N+1]; also seeds cursor[]
__global__ void k_scan(const int* __restrict__ cnt, int* __restrict__ off,
                       int* __restrict__ cursor, int N) {
    __shared__ int sums[1024];
    int t = threadIdx.x;
    int chunk = (N + 1023) / 1024;
    int start = t * chunk, end = min(start + chunk, N);
    int s = 0;
    for (int i = start; i < end; ++i) s += cnt[i];
    sums[t] = s;
    __syncthreads();
    for (int d = 1; d < 1024; d <<= 1) {
        int v = (t >= d) ? sums[t - d] : 0;
        __syncthreads();
        sums[t] += v;
        __syncthreads();
    }
    int pre = (t == 0) ? 0 : sums[t - 1];
    for (int i = start; i < end; ++i) {
        off[i] = pre; cursor[i] = pre; pre += cnt[i];
    }
    if (t == 1023) off[N] = sums[1023];   // == E
}

__global__ void k_fill(const int* __restrict__ row, const int* __restrict__ col,
                       int* __restrict__ cursor, int* __restrict__ srcs, int E) {
    int e = blockIdx.x * blockDim.x + threadIdx.x;
    if (e >= E) return;
    int pos = atomicAdd(cursor + col[e], 1);
    srcs[pos] = row[e];
}

__global__ void k_dinv(const int* __restrict__ cnt, float* __restrict__ dinv, int N) {
    int i = blockIdx.x * blockDim.x + threadIdx.x;
    if (i < N) dinv[i] = (float)(1.0 / sqrt((double)cnt[i] + 1.0));
}

// ---------------- features ----------------
__global__ void k_h0(const float* __restrict__ x, const float* __restrict__ emb,
                     float* __restrict__ h0, int N) {
    int idx = blockIdx.x * blockDim.x + threadIdx.x;
    long total = (long)N * 127;
    if (idx >= total) return;
    int i = idx / 127;
    int k = idx % 127;
    const float* xr = x + (long)i * 5;
    float v;
    if (k < 62) {
        int id0 = (int)xr[0];
        v = emb[(long)id0 * 62 + k];
    } else if (k < 124) {
        int id1 = (int)xr[1];
        v = emb[(long)id1 * 62 + (k - 62)];
    } else {
        v = xr[2 + (k - 124)];
    }
    h0[idx] = v;
}

// ---------------- dense hw = h @ W ----------------
__global__ void k_hw(const float* __restrict__ h, int ld, const float* __restrict__ W,
                     int Din, int Dout, float* __restrict__ hw, int N) {
    int idx = blockIdx.x * blockDim.x + threadIdx.x;
    long total = (long)N * Dout;
    if (idx >= total) return;
    int i = idx / Dout;
    int o = idx % Dout;
    const float* hr = h + (long)i * ld;
    double a0 = 0.0, a1 = 0.0;
    int k = 0;
    for (; k + 1 < Din; k += 2) {
        a0 += (double)hr[k]     * (double)W[(long)k * Dout + o];
        a1 += (double)hr[k + 1] * (double)W[(long)(k + 1) * Dout + o];
    }
    if (k < Din) a0 += (double)hr[k] * (double)W[(long)k * Dout + o];
    hw[idx] = (float)(a0 + a1);
}

// ---------------- fused gather + self + bias + activation ----------------
template<int DOUT>
__global__ void k_gather(const int* __restrict__ off, const int* __restrict__ srcs,
                         const float* __restrict__ dinv, const float* __restrict__ hw,
                         const float* __restrict__ b, float* __restrict__ out,
                         int N, int mode) {
    int idx = blockIdx.x * blockDim.x + threadIdx.x;
    if (idx >= N * DOUT) return;
    int c = idx / DOUT;
    int o = idx % DOUT;
    int e0 = off[c], e1 = off[c + 1];
    double dc = (double)dinv[c];
    double a0 = (double)hw[(long)c * DOUT + o] * dc;  // self-loop term
    double a1 = 0.0;
    int e = e0;
    for (; e + 1 < e1; e += 2) {
        int r0 = srcs[e], r1 = srcs[e + 1];
        a0 += (double)hw[(long)r0 * DOUT + o] * (double)dinv[r0];
        a1 += (double)hw[(long)r1 * DOUT + o] * (double)dinv[r1];
    }
    if (e < e1) {
        int r = srcs[e];
        a0 += (double)hw[(long)r * DOUT + o] * (double)dinv[r];
    }
    double t = (a0 + a1) * dc + (double)b[o];
    double res;
    if (mode == 0) res = (t >= 0.0) ? t : SLOPE * t;
    else           res = (t >= 0.0) ? 2.0 * t : (1.0 + SLOPE) * t;
    out[idx] = (float)res;
}

// ---------------- FC head ----------------
// part[bl, j] = sum_{i in chunk(bl)} v[i] * Wf1[i, j]; 512 blocks, 4-way ILP
__global__ void k_fc1a(const float* __restrict__ v, const float* __restrict__ Wf1,
                       double* __restrict__ part, int N, int chunk) {
    int j = threadIdx.x;            // 0..127
    int bl = blockIdx.x;            // 0..FC1_BLOCKS-1
    int i0 = bl * chunk, i1 = min(i0 + chunk, N);
    double a0 = 0.0, a1 = 0.0, a2 = 0.0, a3 = 0.0;
    int i = i0;
    for (; i + 3 < i1; i += 4) {
        a0 += (double)v[i]     * (double)Wf1[(long)i * 128 + j];
        a1 += (double)v[i + 1] * (double)Wf1[(long)(i + 1) * 128 + j];
        a2 += (double)v[i + 2] * (double)Wf1[(long)(i + 2) * 128 + j];
        a3 += (double)v[i + 3] * (double)Wf1[(long)(i + 3) * 128 + j];
    }
    for (; i < i1; ++i)
        a0 += (double)v[i] * (double)Wf1[(long)i * 128 + j];
    part[bl * 128 + j] = (a0 + a1) + (a2 + a3);
}

// merged: o1 = relu(sum(part) + bf1); out = relu(o1 @ Wf2 + bf2)
__global__ void k_head(const double* __restrict__ part, const float* __restrict__ bf1,
                       const float* __restrict__ Wf2, const float* __restrict__ bf2,
                       float* __restrict__ out, int nb) {
    __shared__ double o1[128];
    int j = threadIdx.x;
    double a0 = 0.0, a1 = 0.0;
    int bl = 0;
    for (; bl + 1 < nb; bl += 2) {
        a0 += part[bl * 128 + j];
        a1 += part[(bl + 1) * 128 + j];
    }
    if (bl < nb) a0 += part[bl * 128 + j];
    double t = a0 + a1 + (double)bf1[j];
    o1[j] = (t > 0.0) ? t : 0.0;
    __syncthreads();
    double acc = 0.0;
    for (int k = 0; k < 128; ++k)
        acc += o1[k] * (double)Wf2[(long)k * 128 + j];
    double u = acc + (double)bf2[j];
    out[j] = (float)((u > 0.0) ? u : 0.0);
}

// ---------------- layer driver ----------------
template<int DOUT>
static void run_gcn(const float* hin, int ld, const float* W, const float* b,
                    int Din, int mode,
                    const int* off, const int* srcs, const float* dinv,
                    float* HW, float* hout, int N, hipStream_t stream) {
    k_hw<<<cdiv_l((long)N * DOUT, 256), 256, 0, stream>>>(hin, ld, W, Din, DOUT, HW, N);
    k_gather<DOUT><<<cdiv_l((long)N * DOUT, 256), 256, 0, stream>>>(
        off, srcs, dinv, HW, b, hout, N, mode);
}

extern "C" void kernel_launch(void* const* d_in, const int* in_sizes, int n_in,
                              void* d_out, int out_size, void* d_ws, size_t ws_size,
                              hipStream_t stream) {
    const float* x   = (const float*)d_in[0];
    const int*   ei  = (const int*)d_in[1];
    const float* emb = (const float*)d_in[2];
    const float* W1  = (const float*)d_in[3];
    const float* b1  = (const float*)d_in[4];
    const float* W2  = (const float*)d_in[5];
    const float* b2  = (const float*)d_in[6];
    const float* W3  = (const float*)d_in[7];
    const float* b3  = (const float*)d_in[8];
    const float* W4  = (const float*)d_in[9];
    const float* b4  = (const float*)d_in[10];
    const float* W5  = (const float*)d_in[11];
    const float* b5  = (const float*)d_in[12];
    const float* Wf1 = (const float*)d_in[13];
    const float* bf1 = (const float*)d_in[14];
    const float* Wf2 = (const float*)d_in[15];
    const float* bf2 = (const float*)d_in[16];

    const int N = in_sizes[0] / 5;
    const int E = in_sizes[1] / 2;
    const int* row = ei;       // edge_index[0]
    const int* col = ei + E;   // edge_index[1]

    // --- workspace carving ---
    char* ws = (char*)d_ws;
    size_t off_b = 0;
    auto alloc = [&](size_t bytes) -> void* {
        void* p = ws + off_b;
        off_b += (bytes + 255) & ~(size_t)255;
        return p;
    };
    int*   cnt    = (int*)alloc((size_t)N * sizeof(int));
    int*   offcsr = (int*)alloc((size_t)(N + 1) * sizeof(int));
    int*   cursor = (int*)alloc((size_t)N * sizeof(int));
    int*   srcs   = (int*)alloc((size_t)E * sizeof(int));
    float* dinv   = (float*)alloc((size_t)N * sizeof(float));
    float* H0     = (float*)alloc((size_t)N * 127 * sizeof(float)); // h0; reused h2,h4
    float* HW     = (float*)alloc((size_t)N * 64 * sizeof(float));
    float* HB     = (float*)alloc((size_t)N * 64 * sizeof(float));  // h1; reused h3
    float* V      = (float*)alloc((size_t)N * sizeof(float));
    double* part  = (double*)alloc((size_t)FC1_BLOCKS * 128 * sizeof(double));

    // --- CSR build + dinv ---
    hipMemsetAsync(cnt, 0, (size_t)N * sizeof(int), stream);
    k_count<<<cdiv_l(E, 256), 256, 0, stream>>>(col, cnt, E);
    k_scan<<<1, 1024, 0, stream>>>(cnt, offcsr, cursor, N);
    k_fill<<<cdiv_l(E, 256), 256, 0, stream>>>(row, col, cursor, srcs, E);
    k_dinv<<<cdiv_l(N, 256), 256, 0, stream>>>(cnt, dinv, N);

    // --- input features ---
    k_h0<<<cdiv_l((long)N * 127, 256), 256, 0, stream>>>(x, emb, H0, N);

    // --- 5 GCN layers ---
    run_gcn<64>(H0, 127, W1, b1, 127, 0, offcsr, srcs, dinv, HW, HB, N, stream);
    run_gcn<32>(HB,  64, W2, b2,  64, 0, offcsr, srcs, dinv, HW, H0, N, stream);
    run_gcn<32>(H0,  32, W3, b3,  32, 1, offcsr, srcs, dinv, HW, HB, N, stream);
    run_gcn<32>(HB,  32, W4, b4,  32, 1, offcsr, srcs, dinv, HW, H0, N, stream);
    run_gcn<1> (H0,  32, W5, b5,  32, 0, offcsr, srcs, dinv, HW, V,  N, stream);

    // --- FC head ---
    int chunk = (N + FC1_BLOCKS - 1) / FC1_BLOCKS;
    k_fc1a<<<FC1_BLOCKS, 128, 0, stream>>>(V, Wf1, part, N, chunk);
    k_head<<<1, 128, 0, stream>>>(part, bf1, Wf2, bf2, (float*)d_out, FC1_BLOCKS);
}

// Round 4
// 685.107 us; speedup vs baseline: 2.6774x; 1.2287x over previous
//
#include <hip/hip_runtime.h>
#include <math.h>

#define SLOPE 0.01f
#define FC1_BLOCKS 512

// ---------------------------------------------------------------------------
// R1: scatter-atomics -> CSR gather (613 MB/layer atomic writes eliminated).
// R2: fc1a parallelism (64 -> 512 blocks).
// R3: drop f64 from GCN path. Profile showed k_hw at 136us / 149 GB/s /
// VALU 28%: the 2x v_cvt_f64_f32 per FMA tripled VALU work and the f64 chain
// blocked issue. f32 error ~1e-10 abs at 3.5e-5 output scale vs 7e-7
// threshold. float4 register blocking: 4 outputs/thread = 4 indep chains,
// vectorized W/hw loads, 4x amortized srcs/dinv loads in gather.
// FC1 (38k-term dot) keeps f64 accumulation -- it's memory-bound, f64 free.
// ---------------------------------------------------------------------------

static inline int cdiv_l(long a, int b) { return (int)((a + (long)b - 1) / (long)b); }

// ---------------- CSR build ----------------
__global__ void k_count(const int* __restrict__ col, int* __restrict__ cnt, int E) {
    int e = blockIdx.x * blockDim.x + threadIdx.x;
    if (e < E) atomicAdd(cnt + col[e], 1);
}

__global__ void k_scan(const int* __restrict__ cnt, int* __restrict__ off,
                       int* __restrict__ cursor, int N) {
    __shared__ int sums[1024];
    int t = threadIdx.x;
    int chunk = (N + 1023) / 1024;
    int start = t * chunk, end = min(start + chunk, N);
    int s = 0;
    for (int i = start; i < end; ++i) s += cnt[i];
    sums[t] = s;
    __syncthreads();
    for (int d = 1; d < 1024; d <<= 1) {
        int v = (t >= d) ? sums[t - d] : 0;
        __syncthreads();
        sums[t] += v;
        __syncthreads();
    }
    int pre = (t == 0) ? 0 : sums[t - 1];
    for (int i = start; i < end; ++i) {
        off[i] = pre; cursor[i] = pre; pre += cnt[i];
    }
    if (t == 1023) off[N] = sums[1023];
}

__global__ void k_fill(const int* __restrict__ row, const int* __restrict__ col,
                       int* __restrict__ cursor, int* __restrict__ srcs, int E) {
    int e = blockIdx.x * blockDim.x + threadIdx.x;
    if (e >= E) return;
    int pos = atomicAdd(cursor + col[e], 1);
    srcs[pos] = row[e];
}

__global__ void k_dinv(const int* __restrict__ cnt, float* __restrict__ dinv, int N) {
    int i = blockIdx.x * blockDim.x + threadIdx.x;
    if (i < N) dinv[i] = (float)(1.0 / sqrt((double)cnt[i] + 1.0));
}

// ---------------- features ----------------
__global__ void k_h0(const float* __restrict__ x, const float* __restrict__ emb,
                     float* __restrict__ h0, int N) {
    int idx = blockIdx.x * blockDim.x + threadIdx.x;
    long total = (long)N * 127;
    if (idx >= total) return;
    int i = idx / 127;
    int k = idx % 127;
    const float* xr = x + (long)i * 5;
    float v;
    if (k < 62) {
        int id0 = (int)xr[0];
        v = emb[(long)id0 * 62 + k];
    } else if (k < 124) {
        int id1 = (int)xr[1];
        v = emb[(long)id1 * 62 + (k - 62)];
    } else {
        v = xr[2 + (k - 124)];
    }
    h0[idx] = v;
}

// ---------------- dense hw = h @ W, 4 outputs/thread ----------------
// DOUT multiple of 4. thread -> (i = tid/(DOUT/4), q = tid%(DOUT/4)).
template<int DIN, int DOUT>
__global__ void k_hw_v4(const float* __restrict__ h, int ld, const float* __restrict__ W,
                        float* __restrict__ hw, int N) {
    constexpr int Q = DOUT / 4;
    int tid = blockIdx.x * blockDim.x + threadIdx.x;
    if (tid >= N * Q) return;
    int i = tid / Q;
    int q = tid % Q;
    const float* hr = h + (long)i * ld;
    float4 acc = make_float4(0.f, 0.f, 0.f, 0.f);
#pragma unroll 4
    for (int k = 0; k < DIN; ++k) {
        float hk = hr[k];
        float4 w = *(const float4*)(W + (long)k * DOUT + 4 * q);
        acc.x += hk * w.x; acc.y += hk * w.y;
        acc.z += hk * w.z; acc.w += hk * w.w;
    }
    *(float4*)(hw + (long)i * DOUT + 4 * q) = acc;
}

// DOUT=1 special case (L5): thread per node
__global__ void k_hw_d1(const float* __restrict__ h, const float* __restrict__ W,
                        float* __restrict__ hw, int N) {
    int i = blockIdx.x * blockDim.x + threadIdx.x;
    if (i >= N) return;
    const float* hr = h + (long)i * 32;
    float acc = 0.f;
#pragma unroll
    for (int k = 0; k < 32; ++k) acc += hr[k] * W[k];
    hw[i] = acc;
}

// ---------------- fused gather + self + bias + activation ----------------
template<int DOUT>
__global__ void k_gather_v4(const int* __restrict__ off, const int* __restrict__ srcs,
                            const float* __restrict__ dinv, const float* __restrict__ hw,
                            const float* __restrict__ b, float* __restrict__ out,
                            int N, int mode) {
    constexpr int Q = DOUT / 4;
    int tid = blockIdx.x * blockDim.x + threadIdx.x;
    if (tid >= N * Q) return;
    int c = tid / Q;
    int q = tid % Q;
    int e0 = off[c], e1 = off[c + 1];
    float dc = dinv[c];
    float4 self = *(const float4*)(hw + (long)c * DOUT + 4 * q);
    float4 acc = make_float4(self.x * dc, self.y * dc, self.z * dc, self.w * dc);
    for (int e = e0; e < e1; ++e) {
        int r = srcs[e];
        float dr = dinv[r];
        float4 v = *(const float4*)(hw + (long)r * DOUT + 4 * q);
        acc.x += v.x * dr; acc.y += v.y * dr;
        acc.z += v.z * dr; acc.w += v.w * dr;
    }
    float4 bb = *(const float4*)(b + 4 * q);
    float t0 = acc.x * dc + bb.x, t1 = acc.y * dc + bb.y;
    float t2 = acc.z * dc + bb.z, t3 = acc.w * dc + bb.w;
    float4 res;
    if (mode == 0) {
        res.x = (t0 >= 0.f) ? t0 : SLOPE * t0;
        res.y = (t1 >= 0.f) ? t1 : SLOPE * t1;
        res.z = (t2 >= 0.f) ? t2 : SLOPE * t2;
        res.w = (t3 >= 0.f) ? t3 : SLOPE * t3;
    } else {
        res.x = (t0 >= 0.f) ? 2.f * t0 : (1.f + SLOPE) * t0;
        res.y = (t1 >= 0.f) ? 2.f * t1 : (1.f + SLOPE) * t1;
        res.z = (t2 >= 0.f) ? 2.f * t2 : (1.f + SLOPE) * t2;
        res.w = (t3 >= 0.f) ? 2.f * t3 : (1.f + SLOPE) * t3;
    }
    *(float4*)(out + (long)c * DOUT + 4 * q) = res;
}

// DOUT=1 (L5): thread per node, lrelu
__global__ void k_gather_d1(const int* __restrict__ off, const int* __restrict__ srcs,
                            const float* __restrict__ dinv, const float* __restrict__ hw,
                            const float* __restrict__ b, float* __restrict__ out, int N) {
    int c = blockIdx.x * blockDim.x + threadIdx.x;
    if (c >= N) return;
    int e0 = off[c], e1 = off[c + 1];
    float dc = dinv[c];
    float acc = hw[c] * dc;
    for (int e = e0; e < e1; ++e) {
        int r = srcs[e];
        acc += hw[r] * dinv[r];
    }
    float t = acc * dc + b[0];
    out[c] = (t >= 0.f) ? t : SLOPE * t;
}

// ---------------- FC head ----------------
__global__ void k_fc1a(const float* __restrict__ v, const float* __restrict__ Wf1,
                       double* __restrict__ part, int N, int chunk) {
    int j = threadIdx.x;
    int bl = blockIdx.x;
    int i0 = bl * chunk, i1 = min(i0 + chunk, N);
    double a0 = 0.0, a1 = 0.0, a2 = 0.0, a3 = 0.0;
    int i = i0;
    for (; i + 3 < i1; i += 4) {
        a0 += (double)v[i]     * (double)Wf1[(long)i * 128 + j];
        a1 += (double)v[i + 1] * (double)Wf1[(long)(i + 1) * 128 + j];
        a2 += (double)v[i + 2] * (double)Wf1[(long)(i + 2) * 128 + j];
        a3 += (double)v[i + 3] * (double)Wf1[(long)(i + 3) * 128 + j];
    }
    for (; i < i1; ++i)
        a0 += (double)v[i] * (double)Wf1[(long)i * 128 + j];
    part[bl * 128 + j] = (a0 + a1) + (a2 + a3);
}

__global__ void k_head(const double* __restrict__ part, const float* __restrict__ bf1,
                       const float* __restrict__ Wf2, const float* __restrict__ bf2,
                       float* __restrict__ out, int nb) {
    __shared__ double o1[128];
    int j = threadIdx.x;
    double a0 = 0.0, a1 = 0.0;
    int bl = 0;
    for (; bl + 1 < nb; bl += 2) {
        a0 += part[bl * 128 + j];
        a1 += part[(bl + 1) * 128 + j];
    }
    if (bl < nb) a0 += part[bl * 128 + j];
    double t = a0 + a1 + (double)bf1[j];
    o1[j] = (t > 0.0) ? t : 0.0;
    __syncthreads();
    double acc = 0.0;
    for (int k = 0; k < 128; ++k)
        acc += o1[k] * (double)Wf2[(long)k * 128 + j];
    double u = acc + (double)bf2[j];
    out[j] = (float)((u > 0.0) ? u : 0.0);
}

// ---------------- layer driver ----------------
template<int DIN, int DOUT>
static void run_gcn(const float* hin, int ld, const float* W, const float* b, int mode,
                    const int* off, const int* srcs, const float* dinv,
                    float* HW, float* hout, int N, hipStream_t stream) {
    constexpr int Q = DOUT / 4;
    k_hw_v4<DIN, DOUT><<<cdiv_l((long)N * Q, 256), 256, 0, stream>>>(hin, ld, W, HW, N);
    k_gather_v4<DOUT><<<cdiv_l((long)N * Q, 256), 256, 0, stream>>>(
        off, srcs, dinv, HW, b, hout, N, mode);
}

extern "C" void kernel_launch(void* const* d_in, const int* in_sizes, int n_in,
                              void* d_out, int out_size, void* d_ws, size_t ws_size,
                              hipStream_t stream) {
    const float* x   = (const float*)d_in[0];
    const int*   ei  = (const int*)d_in[1];
    const float* emb = (const float*)d_in[2];
    const float* W1  = (const float*)d_in[3];
    const float* b1  = (const float*)d_in[4];
    const float* W2  = (const float*)d_in[5];
    const float* b2  = (const float*)d_in[6];
    const float* W3  = (const float*)d_in[7];
    const float* b3  = (const float*)d_in[8];
    const float* W4  = (const float*)d_in[9];
    const float* b4  = (const float*)d_in[10];
    const float* W5  = (const float*)d_in[11];
    const float* b5  = (const float*)d_in[12];
    const float* Wf1 = (const float*)d_in[13];
    const float* bf1 = (const float*)d_in[14];
    const float* Wf2 = (const float*)d_in[15];
    const float* bf2 = (const float*)d_in[16];

    const int N = in_sizes[0] / 5;
    const int E = in_sizes[1] / 2;
    const int* row = ei;
    const int* col = ei + E;

    // --- workspace carving ---
    char* ws = (char*)d_ws;
    size_t off_b = 0;
    auto alloc = [&](size_t bytes) -> void* {
        void* p = ws + off_b;
        off_b += (bytes + 255) & ~(size_t)255;
        return p;
    };
    int*   cnt    = (int*)alloc((size_t)N * sizeof(int));
    int*   offcsr = (int*)alloc((size_t)(N + 1) * sizeof(int));
    int*   cursor = (int*)alloc((size_t)N * sizeof(int));
    int*   srcs   = (int*)alloc((size_t)E * sizeof(int));
    float* dinv   = (float*)alloc((size_t)N * sizeof(float));
    float* H0     = (float*)alloc((size_t)N * 127 * sizeof(float)); // h0; reused h2,h4
    float* HW     = (float*)alloc((size_t)N * 64 * sizeof(float));
    float* HB     = (float*)alloc((size_t)N * 64 * sizeof(float));  // h1; reused h3
    float* V      = (float*)alloc((size_t)N * sizeof(float));
    double* part  = (double*)alloc((size_t)FC1_BLOCKS * 128 * sizeof(double));

    // --- CSR build + dinv ---
    hipMemsetAsync(cnt, 0, (size_t)N * sizeof(int), stream);
    k_count<<<cdiv_l(E, 256), 256, 0, stream>>>(col, cnt, E);
    k_scan<<<1, 1024, 0, stream>>>(cnt, offcsr, cursor, N);
    k_fill<<<cdiv_l(E, 256), 256, 0, stream>>>(row, col, cursor, srcs, E);
    k_dinv<<<cdiv_l(N, 256), 256, 0, stream>>>(cnt, dinv, N);

    // --- input features ---
    k_h0<<<cdiv_l((long)N * 127, 256), 256, 0, stream>>>(x, emb, H0, N);

    // --- 5 GCN layers ---
    run_gcn<127, 64>(H0, 127, W1, b1, 0, offcsr, srcs, dinv, HW, HB, N, stream);
    run_gcn< 64, 32>(HB,  64, W2, b2, 0, offcsr, srcs, dinv, HW, H0, N, stream);
    run_gcn< 32, 32>(H0,  32, W3, b3, 1, offcsr, srcs, dinv, HW, HB, N, stream);
    run_gcn< 32, 32>(HB,  32, W4, b4, 1, offcsr, srcs, dinv, HW, H0, N, stream);
    // L5: 32 -> 1
    k_hw_d1<<<cdiv_l(N, 256), 256, 0, stream>>>(H0, W5, HW, N);
    k_gather_d1<<<cdiv_l(N, 256), 256, 0, stream>>>(offcsr, srcs, dinv, HW, b5, V, N);

    // --- FC head ---
    int chunk = (N + FC1_BLOCKS - 1) / FC1_BLOCKS;
    k_fc1a<<<FC1_BLOCKS, 128, 0, stream>>>(V, Wf1, part, N, chunk);
    k_head<<<1, 128, 0, stream>>>(part, bf1, Wf2, bf2, (float*)d_out, FC1_BLOCKS);
}

// Round 5
// 681.856 us; speedup vs baseline: 2.6901x; 1.0048x over previous
//
#include <hip/hip_runtime.h>
#include <math.h>

#define SLOPE 0.01f
#define FC1_BLOCKS 512
#define NB 64          // CSR-build buckets; bucket = col / S, S = ceil(N/NB)
#define BCHUNK 2048    // edges per k_bucket block

// ---------------------------------------------------------------------------
// R1: scatter-atomics -> CSR gather (atomics wrote 613 MB/layer to HBM).
// R2: fc1a 64 -> 512 blocks (was 1.2% occupancy, latency-bound).
// R3: f64 -> f32 in GCN path (cvt tax tripled VALU work); float4 blocking.
// R4: k_fill wrote 80 MB for a 4.9 MB array (16x line amplification from
//     random 4B stores). Bucket-sort edges first (k_bucket: LDS histogram +
//     contiguous per-bucket runs, packed (col<<16)|row -- both < 2^16), then
//     fill within L2-resident ~77 KB windows (k_fillb). Also fuse h0
//     construction into the L1 matmul (kills a 39 MB round-trip).
// ---------------------------------------------------------------------------

static inline int cdiv_l(long a, int b) { return (int)((a + (long)b - 1) / (long)b); }

// ---------------- CSR build ----------------
__global__ void k_count(const int* __restrict__ col, int* __restrict__ cnt, int E) {
    int e = blockIdx.x * blockDim.x + threadIdx.x;
    if (e < E) atomicAdd(cnt + col[e], 1);
}

// exclusive scan cnt[N] -> off[N+1]; seeds per-node cursor[] and per-bucket gcur[]
__global__ void k_scan(const int* __restrict__ cnt, int* __restrict__ off,
                       int* __restrict__ cursor, int* __restrict__ gcur,
                       int N, int S) {
    __shared__ int sums[1024];
    int t = threadIdx.x;
    int chunk = (N + 1023) / 1024;
    int start = t * chunk, end = min(start + chunk, N);
    int s = 0;
    for (int i = start; i < end; ++i) s += cnt[i];
    sums[t] = s;
    __syncthreads();
    for (int d = 1; d < 1024; d <<= 1) {
        int v = (t >= d) ? sums[t - d] : 0;
        __syncthreads();
        sums[t] += v;
        __syncthreads();
    }
    int pre = (t == 0) ? 0 : sums[t - 1];
    for (int i = start; i < end; ++i) {
        off[i] = pre; cursor[i] = pre; pre += cnt[i];
    }
    if (t == 1023) off[N] = sums[1023];
    __syncthreads();
    if (t <= NB) {
        int idx = t * S; if (idx > N) idx = N;
        gcur[t] = off[idx];          // bucket b's edge-region start
    }
}

// bucket-sort edges by col/S into ebuf, packed (col<<16)|row (N < 65536)
__global__ void k_bucket(const int* __restrict__ row, const int* __restrict__ col,
                         int* __restrict__ gcur, unsigned int* __restrict__ ebuf,
                         int E, int S) {
    __shared__ int hist[NB], base[NB], lcur[NB];
    int t = threadIdx.x;
    if (t < NB) { hist[t] = 0; lcur[t] = 0; }
    __syncthreads();
    int e0 = blockIdx.x * BCHUNK;
    int e1 = min(e0 + BCHUNK, E);
    for (int e = e0 + t; e < e1; e += blockDim.x)
        atomicAdd(&hist[col[e] / S], 1);
    __syncthreads();
    if (t < NB) base[t] = hist[t] ? atomicAdd(&gcur[t], hist[t]) : 0;
    __syncthreads();
    for (int e = e0 + t; e < e1; e += blockDim.x) {
        int c = col[e], r = row[e];
        int b = c / S;
        int p = base[b] + atomicAdd(&lcur[b], 1);
        ebuf[p] = ((unsigned)c << 16) | (unsigned)r;
    }
}

// fill srcs from bucket-sorted ebuf: all writes land in one L2-resident window
__global__ void k_fillb(const unsigned int* __restrict__ ebuf, int* __restrict__ cursor,
                        int* __restrict__ srcs, int E) {
    int i = blockIdx.x * blockDim.x + threadIdx.x;
    if (i >= E) return;
    unsigned p = ebuf[i];
    int c = (int)(p >> 16), r = (int)(p & 0xFFFFu);
    int pos = atomicAdd(cursor + c, 1);
    srcs[pos] = r;
}

__global__ void k_dinv(const int* __restrict__ cnt, float* __restrict__ dinv, int N) {
    int i = blockIdx.x * blockDim.x + threadIdx.x;
    if (i < N) dinv[i] = (float)(1.0 / sqrt((double)cnt[i] + 1.0));
}

// ---------------- L1 matmul fused with feature construction ----------------
// hw1[i, 4q..4q+3] = sum_k h0[i,k] * W1[k, :], h0 = [emb[id0] | emb[id1] | x[2:5]]
__global__ void k_hw1(const float* __restrict__ x, const float* __restrict__ emb,
                      const float* __restrict__ W1, float* __restrict__ hw, int N) {
    int tid = blockIdx.x * blockDim.x + threadIdx.x;
    if (tid >= N * 16) return;
    int i = tid / 16;
    int q = tid % 16;
    const float* xr = x + (long)i * 5;
    int id0 = (int)xr[0], id1 = (int)xr[1];
    const float* wp = W1 + 4 * q;
    float4 acc = make_float4(0.f, 0.f, 0.f, 0.f);
    const float* ep = emb + (long)id0 * 62;
#pragma unroll 2
    for (int k = 0; k < 62; ++k) {
        float hk = ep[k];
        float4 w = *(const float4*)(wp + (long)k * 64);
        acc.x += hk * w.x; acc.y += hk * w.y; acc.z += hk * w.z; acc.w += hk * w.w;
    }
    ep = emb + (long)id1 * 62;
#pragma unroll 2
    for (int k = 0; k < 62; ++k) {
        float hk = ep[k];
        float4 w = *(const float4*)(wp + (long)(62 + k) * 64);
        acc.x += hk * w.x; acc.y += hk * w.y; acc.z += hk * w.z; acc.w += hk * w.w;
    }
#pragma unroll
    for (int k = 0; k < 3; ++k) {
        float hk = xr[2 + k];
        float4 w = *(const float4*)(wp + (long)(124 + k) * 64);
        acc.x += hk * w.x; acc.y += hk * w.y; acc.z += hk * w.z; acc.w += hk * w.w;
    }
    *(float4*)(hw + (long)i * 64 + 4 * q) = acc;
}

// ---------------- dense hw = h @ W, 4 outputs/thread ----------------
template<int DIN, int DOUT>
__global__ void k_hw_v4(const float* __restrict__ h, int ld, const float* __restrict__ W,
                        float* __restrict__ hw, int N) {
    constexpr int Q = DOUT / 4;
    int tid = blockIdx.x * blockDim.x + threadIdx.x;
    if (tid >= N * Q) return;
    int i = tid / Q;
    int q = tid % Q;
    const float* hr = h + (long)i * ld;
    float4 acc = make_float4(0.f, 0.f, 0.f, 0.f);
#pragma unroll 4
    for (int k = 0; k < DIN; ++k) {
        float hk = hr[k];
        float4 w = *(const float4*)(W + (long)k * DOUT + 4 * q);
        acc.x += hk * w.x; acc.y += hk * w.y; acc.z += hk * w.z; acc.w += hk * w.w;
    }
    *(float4*)(hw + (long)i * DOUT + 4 * q) = acc;
}

__global__ void k_hw_d1(const float* __restrict__ h, const float* __restrict__ W,
                        float* __restrict__ hw, int N) {
    int i = blockIdx.x * blockDim.x + threadIdx.x;
    if (i >= N) return;
    const float* hr = h + (long)i * 32;
    float acc = 0.f;
#pragma unroll
    for (int k = 0; k < 32; ++k) acc += hr[k] * W[k];
    hw[i] = acc;
}

// ---------------- fused gather + self + bias + activation ----------------
template<int DOUT>
__global__ void k_gather_v4(const int* __restrict__ off, const int* __restrict__ srcs,
                            const float* __restrict__ dinv, const float* __restrict__ hw,
                            const float* __restrict__ b, float* __restrict__ out,
                            int N, int mode) {
    constexpr int Q = DOUT / 4;
    int tid = blockIdx.x * blockDim.x + threadIdx.x;
    if (tid >= N * Q) return;
    int c = tid / Q;
    int q = tid % Q;
    int e0 = off[c], e1 = off[c + 1];
    float dc = dinv[c];
    float4 self = *(const float4*)(hw + (long)c * DOUT + 4 * q);
    float4 acc = make_float4(self.x * dc, self.y * dc, self.z * dc, self.w * dc);
    for (int e = e0; e < e1; ++e) {
        int r = srcs[e];
        float dr = dinv[r];
        float4 v = *(const float4*)(hw + (long)r * DOUT + 4 * q);
        acc.x += v.x * dr; acc.y += v.y * dr;
        acc.z += v.z * dr; acc.w += v.w * dr;
    }
    float4 bb = *(const float4*)(b + 4 * q);
    float t0 = acc.x * dc + bb.x, t1 = acc.y * dc + bb.y;
    float t2 = acc.z * dc + bb.z, t3 = acc.w * dc + bb.w;
    float4 res;
    if (mode == 0) {
        res.x = (t0 >= 0.f) ? t0 : SLOPE * t0;
        res.y = (t1 >= 0.f) ? t1 : SLOPE * t1;
        res.z = (t2 >= 0.f) ? t2 : SLOPE * t2;
        res.w = (t3 >= 0.f) ? t3 : SLOPE * t3;
    } else {
        res.x = (t0 >= 0.f) ? 2.f * t0 : (1.f + SLOPE) * t0;
        res.y = (t1 >= 0.f) ? 2.f * t1 : (1.f + SLOPE) * t1;
        res.z = (t2 >= 0.f) ? 2.f * t2 : (1.f + SLOPE) * t2;
        res.w = (t3 >= 0.f) ? 2.f * t3 : (1.f + SLOPE) * t3;
    }
    *(float4*)(out + (long)c * DOUT + 4 * q) = res;
}

__global__ void k_gather_d1(const int* __restrict__ off, const int* __restrict__ srcs,
                            const float* __restrict__ dinv, const float* __restrict__ hw,
                            const float* __restrict__ b, float* __restrict__ out, int N) {
    int c = blockIdx.x * blockDim.x + threadIdx.x;
    if (c >= N) return;
    int e0 = off[c], e1 = off[c + 1];
    float dc = dinv[c];
    float acc = hw[c] * dc;
    for (int e = e0; e < e1; ++e) {
        int r = srcs[e];
        acc += hw[r] * dinv[r];
    }
    float t = acc * dc + b[0];
    out[c] = (t >= 0.f) ? t : SLOPE * t;
}

// ---------------- FC head ----------------
__global__ void k_fc1a(const float* __restrict__ v, const float* __restrict__ Wf1,
                       double* __restrict__ part, int N, int chunk) {
    int j = threadIdx.x;
    int bl = blockIdx.x;
    int i0 = bl * chunk, i1 = min(i0 + chunk, N);
    double a0 = 0.0, a1 = 0.0, a2 = 0.0, a3 = 0.0;
    int i = i0;
    for (; i + 3 < i1; i += 4) {
        a0 += (double)v[i]     * (double)Wf1[(long)i * 128 + j];
        a1 += (double)v[i + 1] * (double)Wf1[(long)(i + 1) * 128 + j];
        a2 += (double)v[i + 2] * (double)Wf1[(long)(i + 2) * 128 + j];
        a3 += (double)v[i + 3] * (double)Wf1[(long)(i + 3) * 128 + j];
    }
    for (; i < i1; ++i)
        a0 += (double)v[i] * (double)Wf1[(long)i * 128 + j];
    part[bl * 128 + j] = (a0 + a1) + (a2 + a3);
}

__global__ void k_head(const double* __restrict__ part, const float* __restrict__ bf1,
                       const float* __restrict__ Wf2, const float* __restrict__ bf2,
                       float* __restrict__ out, int nb) {
    __shared__ double o1[128];
    int j = threadIdx.x;
    double a0 = 0.0, a1 = 0.0;
    int bl = 0;
    for (; bl + 1 < nb; bl += 2) {
        a0 += part[bl * 128 + j];
        a1 += part[(bl + 1) * 128 + j];
    }
    if (bl < nb) a0 += part[bl * 128 + j];
    double t = a0 + a1 + (double)bf1[j];
    o1[j] = (t > 0.0) ? t : 0.0;
    __syncthreads();
    double acc = 0.0;
    for (int k = 0; k < 128; ++k)
        acc += o1[k] * (double)Wf2[(long)k * 128 + j];
    double u = acc + (double)bf2[j];
    out[j] = (float)((u > 0.0) ? u : 0.0);
}

// ---------------- layer driver ----------------
template<int DIN, int DOUT>
static void run_gcn(const float* hin, int ld, const float* W, const float* b, int mode,
                    const int* off, const int* srcs, const float* dinv,
                    float* HW, float* hout, int N, hipStream_t stream) {
    constexpr int Q = DOUT / 4;
    k_hw_v4<DIN, DOUT><<<cdiv_l((long)N * Q, 256), 256, 0, stream>>>(hin, ld, W, HW, N);
    k_gather_v4<DOUT><<<cdiv_l((long)N * Q, 256), 256, 0, stream>>>(
        off, srcs, dinv, HW, b, hout, N, mode);
}

extern "C" void kernel_launch(void* const* d_in, const int* in_sizes, int n_in,
                              void* d_out, int out_size, void* d_ws, size_t ws_size,
                              hipStream_t stream) {
    const float* x   = (const float*)d_in[0];
    const int*   ei  = (const int*)d_in[1];
    const float* emb = (const float*)d_in[2];
    const float* W1  = (const float*)d_in[3];
    const float* b1  = (const float*)d_in[4];
    const float* W2  = (const float*)d_in[5];
    const float* b2  = (const float*)d_in[6];
    const float* W3  = (const float*)d_in[7];
    const float* b3  = (const float*)d_in[8];
    const float* W4  = (const float*)d_in[9];
    const float* b4  = (const float*)d_in[10];
    const float* W5  = (const float*)d_in[11];
    const float* b5  = (const float*)d_in[12];
    const float* Wf1 = (const float*)d_in[13];
    const float* bf1 = (const float*)d_in[14];
    const float* Wf2 = (const float*)d_in[15];
    const float* bf2 = (const float*)d_in[16];

    const int N = in_sizes[0] / 5;
    const int E = in_sizes[1] / 2;
    const int* row = ei;
    const int* col = ei + E;
    const int S = (N + NB - 1) / NB;

    // --- workspace carving ---
    char* ws = (char*)d_ws;
    size_t off_b = 0;
    auto alloc = [&](size_t bytes) -> void* {
        void* p = ws + off_b;
        off_b += (bytes + 255) & ~(size_t)255;
        return p;
    };
    int*   cnt    = (int*)alloc((size_t)N * sizeof(int));
    int*   offcsr = (int*)alloc((size_t)(N + 1) * sizeof(int));
    int*   cursor = (int*)alloc((size_t)N * sizeof(int));
    int*   gcur   = (int*)alloc((size_t)(NB + 1) * sizeof(int));
    int*   srcs   = (int*)alloc((size_t)E * sizeof(int));
    unsigned int* ebuf = (unsigned int*)alloc((size_t)E * sizeof(unsigned int));
    float* dinv   = (float*)alloc((size_t)N * sizeof(float));
    float* HA     = (float*)alloc((size_t)N * 64 * sizeof(float)); // h2, h4
    float* HW     = (float*)alloc((size_t)N * 64 * sizeof(float));
    float* HB     = (float*)alloc((size_t)N * 64 * sizeof(float)); // h1, h3
    float* V      = (float*)alloc((size_t)N * sizeof(float));
    double* part  = (double*)alloc((size_t)FC1_BLOCKS * 128 * sizeof(double));

    // --- CSR build + dinv ---
    hipMemsetAsync(cnt, 0, (size_t)N * sizeof(int), stream);
    k_count<<<cdiv_l(E, 256), 256, 0, stream>>>(col, cnt, E);
    k_scan<<<1, 1024, 0, stream>>>(cnt, offcsr, cursor, gcur, N, S);
    k_bucket<<<cdiv_l(E, BCHUNK), 256, 0, stream>>>(row, col, gcur, ebuf, E, S);
    k_fillb<<<cdiv_l(E, 256), 256, 0, stream>>>(ebuf, cursor, srcs, E);
    k_dinv<<<cdiv_l(N, 256), 256, 0, stream>>>(cnt, dinv, N);

    // --- 5 GCN layers (L1 matmul fused with h0 construction) ---
    k_hw1<<<cdiv_l((long)N * 16, 256), 256, 0, stream>>>(x, emb, W1, HW, N);
    k_gather_v4<64><<<cdiv_l((long)N * 16, 256), 256, 0, stream>>>(
        offcsr, srcs, dinv, HW, b1, HB, N, 0);
    run_gcn<64, 32>(HB, 64, W2, b2, 0, offcsr, srcs, dinv, HW, HA, N, stream);
    run_gcn<32, 32>(HA, 32, W3, b3, 1, offcsr, srcs, dinv, HW, HB, N, stream);
    run_gcn<32, 32>(HB, 32, W4, b4, 1, offcsr, srcs, dinv, HW, HA, N, stream);
    k_hw_d1<<<cdiv_l(N, 256), 256, 0, stream>>>(HA, W5, HW, N);
    k_gather_d1<<<cdiv_l(N, 256), 256, 0, stream>>>(offcsr, srcs, dinv, HW, b5, V, N);

    // --- FC head ---
    int chunk = (N + FC1_BLOCKS - 1) / FC1_BLOCKS;
    k_fc1a<<<FC1_BLOCKS, 128, 0, stream>>>(V, Wf1, part, N, chunk);
    k_head<<<1, 128, 0, stream>>>(part, bf1, Wf2, bf2, (float*)d_out, FC1_BLOCKS);
}

// Round 6
// 518.987 us; speedup vs baseline: 3.5344x; 1.3138x over previous
//
#include <hip/hip_runtime.h>
#include <math.h>

#define SLOPE 0.01f
#define FC1_BLOCKS 512
#define NBLK 256       // scan chunks
#define NB 64          // CSR buckets = NBLK/4 (so bucket starts = bloff[4b])
#define BCHUNK 2048    // edges per k_bucket block

// ---------------------------------------------------------------------------
// R1: scatter-atomics -> CSR gather (atomics wrote 613 MB/layer to HBM).
// R2: fc1a 64 -> 512 blocks (was 1.2% occupancy, latency-bound).
// R3: f64 -> f32 in GCN path; float4 register blocking.
// R4: bucket-sorted CSR fill (k_fill had 16x write amplification).
// R5 fixes, per profile: (a) k_scan was a single-block 82us kernel ->
//     3-kernel multi-block scan (~12us), dinv folded into scanC;
//     (b) h0-into-matmul fusion REGRESSED (84us, latency chain on random emb
//     loads) -> revert to padded k_h0 (ld=128) + all-float4 k_hw, and overlap
//     count/h0/W1pad in one merged k_front launch; (c) fold dinv into the
//     hw store (hws = hw*dinv): t = dc*(hws[c] + sum hws[r]) + b -- one fewer
//     load and one fewer FMA per edge in every gather inner loop.
// ---------------------------------------------------------------------------

static inline int cdiv_l(long a, int b) { return (int)((a + (long)b - 1) / (long)b); }

// ---------------- merged front: count atomics | h0 build | W1 pad ----------------
__global__ void k_front(const int* __restrict__ col, int* __restrict__ cnt, int E,
                        const float* __restrict__ x, const float* __restrict__ emb,
                        float* __restrict__ h0, int N,
                        const float* __restrict__ W1, float* __restrict__ W1p,
                        int countBlocks, int h0Blocks) {
    int b = blockIdx.x;
    if (b < countBlocks) {
        int e = b * 256 + threadIdx.x;
        if (e < E) atomicAdd(cnt + col[e], 1);
        return;
    }
    b -= countBlocks;
    if (b < h0Blocks) {
        int idx = b * 256 + threadIdx.x;
        if (idx >= N * 128) return;
        int i = idx >> 7;
        int k = idx & 127;
        const float* xr = x + (long)i * 5;
        float v;
        if (k < 62)       v = emb[(long)((int)xr[0]) * 62 + k];
        else if (k < 124) v = emb[(long)((int)xr[1]) * 62 + (k - 62)];
        else if (k < 127) v = xr[2 + (k - 124)];
        else              v = 0.f;
        h0[idx] = v;
        return;
    }
    b -= h0Blocks;
    {   // W1 pad: 128x64, row 127 = 0
        int idx = b * 256 + threadIdx.x;
        if (idx >= 128 * 64) return;
        int k = idx >> 6;
        W1p[idx] = (k < 127) ? W1[idx] : 0.f;
    }
}

// ---------------- multi-block scan ----------------
// A: per-chunk reduce
__global__ void k_scanA(const int* __restrict__ cnt, int* __restrict__ bsum,
                        int N, int chunk) {
    __shared__ int red[256];
    int t = threadIdx.x, b = blockIdx.x;
    int i = b * chunk + t;
    red[t] = (t < chunk && i < N) ? cnt[i] : 0;
    __syncthreads();
    for (int s = 128; s > 0; s >>= 1) {
        if (t < s) red[t] += red[t + s];
        __syncthreads();
    }
    if (t == 0) bsum[b] = red[0];
}

// B: single small block scans the 256 block sums; emits bucket starts + off[N]
__global__ void k_scanB(const int* __restrict__ bsum, int* __restrict__ bloff,
                        int* __restrict__ gcur, int* __restrict__ off, int N) {
    __shared__ int sc[NBLK];
    int t = threadIdx.x;
    int v = bsum[t];
    sc[t] = v;
    __syncthreads();
    for (int d = 1; d < NBLK; d <<= 1) {
        int u = (t >= d) ? sc[t - d] : 0;
        __syncthreads();
        sc[t] += u;
        __syncthreads();
    }
    int excl = sc[t] - v;
    bloff[t] = excl;
    if ((t & 3) == 0) gcur[t >> 2] = excl;   // bucket b starts at chunk 4b
    if (t == NBLK - 1) off[N] = sc[t];       // == E
}

// C: per-chunk Hillis-Steele scan; writes off, cursor, dinv
__global__ void k_scanC(const int* __restrict__ cnt, const int* __restrict__ bloff,
                        int* __restrict__ off, int* __restrict__ cursor,
                        float* __restrict__ dinv, int N, int chunk) {
    __shared__ int sc[256];
    int t = threadIdx.x, b = blockIdx.x;
    int i = b * chunk + t;
    int v = (t < chunk && i < N) ? cnt[i] : 0;
    sc[t] = v;
    __syncthreads();
    for (int d = 1; d < 256; d <<= 1) {
        int u = (t >= d) ? sc[t - d] : 0;
        __syncthreads();
        sc[t] += u;
        __syncthreads();
    }
    if (t < chunk && i < N) {
        int o = bloff[b] + sc[t] - v;
        off[i] = o;
        cursor[i] = o;
        dinv[i] = (float)(1.0 / sqrt((double)v + 1.0));
    }
}

// ---------------- bucket-sort edges, then locality-friendly CSR fill ----------------
__global__ void k_bucket(const int* __restrict__ row, const int* __restrict__ col,
                         int* __restrict__ gcur, unsigned int* __restrict__ ebuf,
                         int E, int S) {
    __shared__ int hist[NB], base[NB], lcur[NB];
    int t = threadIdx.x;
    if (t < NB) { hist[t] = 0; lcur[t] = 0; }
    __syncthreads();
    int e0 = blockIdx.x * BCHUNK;
    int e1 = min(e0 + BCHUNK, E);
    for (int e = e0 + t; e < e1; e += blockDim.x)
        atomicAdd(&hist[col[e] / S], 1);
    __syncthreads();
    if (t < NB) base[t] = hist[t] ? atomicAdd(&gcur[t], hist[t]) : 0;
    __syncthreads();
    for (int e = e0 + t; e < e1; e += blockDim.x) {
        int c = col[e], r = row[e];
        int b = c / S;
        int p = base[b] + atomicAdd(&lcur[b], 1);
        ebuf[p] = ((unsigned)c << 16) | (unsigned)r;
    }
}

__global__ void k_fillb(const unsigned int* __restrict__ ebuf, int* __restrict__ cursor,
                        int* __restrict__ srcs, int E) {
    int i = blockIdx.x * blockDim.x + threadIdx.x;
    if (i >= E) return;
    unsigned p = ebuf[i];
    int c = (int)(p >> 16), r = (int)(p & 0xFFFFu);
    int pos = atomicAdd(cursor + c, 1);
    srcs[pos] = r;
}

// ---------------- dense hws = (h @ W) * dinv, 4 outputs/thread, all-float4 ----------
// DIN, DOUT, ld multiples of 4.
template<int DIN, int DOUT>
__global__ void k_hw_v4(const float* __restrict__ h, int ld, const float* __restrict__ W,
                        const float* __restrict__ dinv, float* __restrict__ hws, int N) {
    constexpr int Q = DOUT / 4;
    int tid = blockIdx.x * blockDim.x + threadIdx.x;
    if (tid >= N * Q) return;
    int i = tid / Q;
    int q = tid % Q;
    const float4* hr4 = (const float4*)(h + (long)i * ld);
    const float* wp = W + 4 * q;
    float4 acc = make_float4(0.f, 0.f, 0.f, 0.f);
#pragma unroll 2
    for (int kk = 0; kk < DIN / 4; ++kk) {
        float4 hv = hr4[kk];
        float4 w0 = *(const float4*)(wp + (long)(4 * kk)     * DOUT);
        float4 w1 = *(const float4*)(wp + (long)(4 * kk + 1) * DOUT);
        float4 w2 = *(const float4*)(wp + (long)(4 * kk + 2) * DOUT);
        float4 w3 = *(const float4*)(wp + (long)(4 * kk + 3) * DOUT);
        acc.x += hv.x * w0.x + hv.y * w1.x + hv.z * w2.x + hv.w * w3.x;
        acc.y += hv.x * w0.y + hv.y * w1.y + hv.z * w2.y + hv.w * w3.y;
        acc.z += hv.x * w0.z + hv.y * w1.z + hv.z * w2.z + hv.w * w3.z;
        acc.w += hv.x * w0.w + hv.y * w1.w + hv.z * w2.w + hv.w * w3.w;
    }
    float di = dinv[i];
    acc.x *= di; acc.y *= di; acc.z *= di; acc.w *= di;
    *(float4*)(hws + (long)i * DOUT + 4 * q) = acc;
}

// L5: DIN=32 -> 1 output, thread per node
__global__ void k_hw_d1(const float* __restrict__ h, const float* __restrict__ W,
                        const float* __restrict__ dinv, float* __restrict__ hws, int N) {
    int i = blockIdx.x * blockDim.x + threadIdx.x;
    if (i >= N) return;
    const float4* hr4 = (const float4*)(h + (long)i * 32);
    float acc = 0.f;
#pragma unroll
    for (int kk = 0; kk < 8; ++kk) {
        float4 hv = hr4[kk];
        acc += hv.x * W[4 * kk] + hv.y * W[4 * kk + 1]
             + hv.z * W[4 * kk + 2] + hv.w * W[4 * kk + 3];
    }
    hws[i] = acc * dinv[i];
}

// ---------------- gather: out[c] = act( dc * (hws[c] + sum_e hws[src]) + b ) --------
template<int DOUT>
__global__ void k_gather_v4(const int* __restrict__ off, const int* __restrict__ srcs,
                            const float* __restrict__ dinv, const float* __restrict__ hws,
                            const float* __restrict__ b, float* __restrict__ out,
                            int N, int mode) {
    constexpr int Q = DOUT / 4;
    int tid = blockIdx.x * blockDim.x + threadIdx.x;
    if (tid >= N * Q) return;
    int c = tid / Q;
    int q = tid % Q;
    int e0 = off[c], e1 = off[c + 1];
    float dc = dinv[c];
    float4 acc = *(const float4*)(hws + (long)c * DOUT + 4 * q);  // self term
    int e = e0;
    for (; e + 3 < e1; e += 4) {
        int r0 = srcs[e], r1 = srcs[e + 1], r2 = srcs[e + 2], r3 = srcs[e + 3];
        float4 v0 = *(const float4*)(hws + (long)r0 * DOUT + 4 * q);
        float4 v1 = *(const float4*)(hws + (long)r1 * DOUT + 4 * q);
        float4 v2 = *(const float4*)(hws + (long)r2 * DOUT + 4 * q);
        float4 v3 = *(const float4*)(hws + (long)r3 * DOUT + 4 * q);
        acc.x += (v0.x + v1.x) + (v2.x + v3.x);
        acc.y += (v0.y + v1.y) + (v2.y + v3.y);
        acc.z += (v0.z + v1.z) + (v2.z + v3.z);
        acc.w += (v0.w + v1.w) + (v2.w + v3.w);
    }
    for (; e < e1; ++e) {
        int r = srcs[e];
        float4 v = *(const float4*)(hws + (long)r * DOUT + 4 * q);
        acc.x += v.x; acc.y += v.y; acc.z += v.z; acc.w += v.w;
    }
    float4 bb = *(const float4*)(b + 4 * q);
    float t0 = acc.x * dc + bb.x, t1 = acc.y * dc + bb.y;
    float t2 = acc.z * dc + bb.z, t3 = acc.w * dc + bb.w;
    float4 res;
    if (mode == 0) {
        res.x = (t0 >= 0.f) ? t0 : SLOPE * t0;
        res.y = (t1 >= 0.f) ? t1 : SLOPE * t1;
        res.z = (t2 >= 0.f) ? t2 : SLOPE * t2;
        res.w = (t3 >= 0.f) ? t3 : SLOPE * t3;
    } else {
        res.x = (t0 >= 0.f) ? 2.f * t0 : (1.f + SLOPE) * t0;
        res.y = (t1 >= 0.f) ? 2.f * t1 : (1.f + SLOPE) * t1;
        res.z = (t2 >= 0.f) ? 2.f * t2 : (1.f + SLOPE) * t2;
        res.w = (t3 >= 0.f) ? 2.f * t3 : (1.f + SLOPE) * t3;
    }
    *(float4*)(out + (long)c * DOUT + 4 * q) = res;
}

__global__ void k_gather_d1(const int* __restrict__ off, const int* __restrict__ srcs,
                            const float* __restrict__ dinv, const float* __restrict__ hws,
                            const float* __restrict__ b, float* __restrict__ out, int N) {
    int c = blockIdx.x * blockDim.x + threadIdx.x;
    if (c >= N) return;
    int e0 = off[c], e1 = off[c + 1];
    float acc = hws[c];
    int e = e0;
    float a1 = 0.f, a2 = 0.f, a3 = 0.f;
    for (; e + 3 < e1; e += 4) {
        acc += hws[srcs[e]];
        a1  += hws[srcs[e + 1]];
        a2  += hws[srcs[e + 2]];
        a3  += hws[srcs[e + 3]];
    }
    for (; e < e1; ++e) acc += hws[srcs[e]];
    float t = (acc + a1 + a2 + a3) * dinv[c] + b[0];
    out[c] = (t >= 0.f) ? t : SLOPE * t;
}

// ---------------- FC head ----------------
__global__ void k_fc1a(const float* __restrict__ v, const float* __restrict__ Wf1,
                       double* __restrict__ part, int N, int chunk) {
    int j = threadIdx.x;
    int bl = blockIdx.x;
    int i0 = bl * chunk, i1 = min(i0 + chunk, N);
    double a0 = 0.0, a1 = 0.0, a2 = 0.0, a3 = 0.0;
    int i = i0;
    for (; i + 3 < i1; i += 4) {
        a0 += (double)v[i]     * (double)Wf1[(long)i * 128 + j];
        a1 += (double)v[i + 1] * (double)Wf1[(long)(i + 1) * 128 + j];
        a2 += (double)v[i + 2] * (double)Wf1[(long)(i + 2) * 128 + j];
        a3 += (double)v[i + 3] * (double)Wf1[(long)(i + 3) * 128 + j];
    }
    for (; i < i1; ++i)
        a0 += (double)v[i] * (double)Wf1[(long)i * 128 + j];
    part[bl * 128 + j] = (a0 + a1) + (a2 + a3);
}

__global__ void k_head(const double* __restrict__ part, const float* __restrict__ bf1,
                       const float* __restrict__ Wf2, const float* __restrict__ bf2,
                       float* __restrict__ out, int nb) {
    __shared__ double o1[128];
    int j = threadIdx.x;
    double a0 = 0.0, a1 = 0.0;
    int bl = 0;
    for (; bl + 1 < nb; bl += 2) {
        a0 += part[bl * 128 + j];
        a1 += part[(bl + 1) * 128 + j];
    }
    if (bl < nb) a0 += part[bl * 128 + j];
    double t = a0 + a1 + (double)bf1[j];
    o1[j] = (t > 0.0) ? t : 0.0;
    __syncthreads();
    double acc = 0.0;
    for (int k = 0; k < 128; ++k)
        acc += o1[k] * (double)Wf2[(long)k * 128 + j];
    double u = acc + (double)bf2[j];
    out[j] = (float)((u > 0.0) ? u : 0.0);
}

// ---------------- layer driver ----------------
template<int DIN, int DOUT>
static void run_gcn(const float* hin, int ld, const float* W, const float* b, int mode,
                    const int* off, const int* srcs, const float* dinv,
                    float* HWS, float* hout, int N, hipStream_t stream) {
    constexpr int Q = DOUT / 4;
    k_hw_v4<DIN, DOUT><<<cdiv_l((long)N * Q, 256), 256, 0, stream>>>(hin, ld, W, dinv, HWS, N);
    k_gather_v4<DOUT><<<cdiv_l((long)N * Q, 256), 256, 0, stream>>>(
        off, srcs, dinv, HWS, b, hout, N, mode);
}

extern "C" void kernel_launch(void* const* d_in, const int* in_sizes, int n_in,
                              void* d_out, int out_size, void* d_ws, size_t ws_size,
                              hipStream_t stream) {
    const float* x   = (const float*)d_in[0];
    const int*   ei  = (const int*)d_in[1];
    const float* emb = (const float*)d_in[2];
    const float* W1  = (const float*)d_in[3];
    const float* b1  = (const float*)d_in[4];
    const float* W2  = (const float*)d_in[5];
    const float* b2  = (const float*)d_in[6];
    const float* W3  = (const float*)d_in[7];
    const float* b3  = (const float*)d_in[8];
    const float* W4  = (const float*)d_in[9];
    const float* b4  = (const float*)d_in[10];
    const float* W5  = (const float*)d_in[11];
    const float* b5  = (const float*)d_in[12];
    const float* Wf1 = (const float*)d_in[13];
    const float* bf1 = (const float*)d_in[14];
    const float* Wf2 = (const float*)d_in[15];
    const float* bf2 = (const float*)d_in[16];

    const int N = in_sizes[0] / 5;
    const int E = in_sizes[1] / 2;
    const int* row = ei;
    const int* col = ei + E;
    const int CHUNK = (N + NBLK - 1) / NBLK;   // scan chunk
    const int S = 4 * CHUNK;                    // bucket width (bucket b = chunks 4b..4b+3)

    // --- workspace carving ---
    char* ws = (char*)d_ws;
    size_t off_b = 0;
    auto alloc = [&](size_t bytes) -> void* {
        void* p = ws + off_b;
        off_b += (bytes + 255) & ~(size_t)255;
        return p;
    };
    int*   cnt    = (int*)alloc((size_t)N * sizeof(int));
    int*   offcsr = (int*)alloc((size_t)(N + 1) * sizeof(int));
    int*   cursor = (int*)alloc((size_t)N * sizeof(int));
    int*   bsum   = (int*)alloc((size_t)NBLK * sizeof(int));
    int*   bloff  = (int*)alloc((size_t)NBLK * sizeof(int));
    int*   gcur   = (int*)alloc((size_t)NB * sizeof(int));
    int*   srcs   = (int*)alloc((size_t)E * sizeof(int));
    unsigned int* ebuf = (unsigned int*)alloc((size_t)E * sizeof(unsigned int));
    float* dinv   = (float*)alloc((size_t)N * sizeof(float));
    float* W1p    = (float*)alloc((size_t)128 * 64 * sizeof(float));
    float* H0     = (float*)alloc((size_t)N * 128 * sizeof(float)); // padded L1 input
    float* HWS    = (float*)alloc((size_t)N * 64 * sizeof(float));
    float* HA     = (float*)alloc((size_t)N * 64 * sizeof(float));  // h2, h4
    float* HB     = (float*)alloc((size_t)N * 64 * sizeof(float));  // h1, h3
    float* V      = (float*)alloc((size_t)N * sizeof(float));
    double* part  = (double*)alloc((size_t)FC1_BLOCKS * 128 * sizeof(double));

    // --- front: zero cnt, then merged (count | h0 | W1pad) ---
    hipMemsetAsync(cnt, 0, (size_t)N * sizeof(int), stream);
    int countBlocks = cdiv_l(E, 256);
    int h0Blocks    = cdiv_l((long)N * 128, 256);
    int padBlocks   = cdiv_l(128 * 64, 256);
    k_front<<<countBlocks + h0Blocks + padBlocks, 256, 0, stream>>>(
        col, cnt, E, x, emb, H0, N, W1, W1p, countBlocks, h0Blocks);

    // --- scan + CSR ---
    k_scanA<<<NBLK, 256, 0, stream>>>(cnt, bsum, N, CHUNK);
    k_scanB<<<1, NBLK, 0, stream>>>(bsum, bloff, gcur, offcsr, N);
    k_scanC<<<NBLK, 256, 0, stream>>>(cnt, bloff, offcsr, cursor, dinv, N, CHUNK);
    k_bucket<<<cdiv_l(E, BCHUNK), 256, 0, stream>>>(row, col, gcur, ebuf, E, S);
    k_fillb<<<cdiv_l(E, 256), 256, 0, stream>>>(ebuf, cursor, srcs, E);

    // --- 5 GCN layers ---
    run_gcn<128, 64>(H0, 128, W1p, b1, 0, offcsr, srcs, dinv, HWS, HB, N, stream);
    run_gcn< 64, 32>(HB,  64, W2,  b2, 0, offcsr, srcs, dinv, HWS, HA, N, stream);
    run_gcn< 32, 32>(HA,  32, W3,  b3, 1, offcsr, srcs, dinv, HWS, HB, N, stream);
    run_gcn< 32, 32>(HB,  32, W4,  b4, 1, offcsr, srcs, dinv, HWS, HA, N, stream);
    k_hw_d1<<<cdiv_l(N, 256), 256, 0, stream>>>(HA, W5, dinv, HWS, N);
    k_gather_d1<<<cdiv_l(N, 256), 256, 0, stream>>>(offcsr, srcs, dinv, HWS, b5, V, N);

    // --- FC head ---
    int chunk = (N + FC1_BLOCKS - 1) / FC1_BLOCKS;
    k_fc1a<<<FC1_BLOCKS, 128, 0, stream>>>(V, Wf1, part, N, chunk);
    k_head<<<1, 128, 0, stream>>>(part, bf1, Wf2, bf2, (float*)d_out, FC1_BLOCKS);
}

// Round 7
// 458.304 us; speedup vs baseline: 4.0023x; 1.1324x over previous
//
#include <hip/hip_runtime.h>
#include <math.h>

#define SLOPE 0.01f
#define FC1_BLOCKS 512
#define NBLK 256       // scan chunks
#define NB 64          // CSR buckets = NBLK/4 (so bucket starts = bloff[4b])
#define BCHUNK 2048    // edges per k_bucket block

// ---------------------------------------------------------------------------
// R1: scatter-atomics -> CSR gather (atomics wrote 613 MB/layer to HBM).
// R2: fc1a 64 -> 512 blocks (was 1.2% occupancy, latency-bound).
// R3: f64 -> f32 in GCN path; float4 register blocking.
// R4: bucket-sorted CSR fill (k_fill had 16x write amplification).
// R5: multi-block scan; un-fused L1 (emb-gather latency chain); hws=hw*dinv.
// R6: k_head was 77us on ONE block (0.02% occ, latency chain over 512x128
//     f64 partials) -- same disease as R2's fc1a. Split: k_fc1b (128 blocks,
//     LDS tree over partials) + k_fc2 (128 blocks, one per output, LDS tree
//     over k). Single-block kernels are only OK when they do ~zero loads.
// ---------------------------------------------------------------------------

static inline int cdiv_l(long a, int b) { return (int)((a + (long)b - 1) / (long)b); }

// ---------------- merged front: count atomics | h0 build | W1 pad ----------------
__global__ void k_front(const int* __restrict__ col, int* __restrict__ cnt, int E,
                        const float* __restrict__ x, const float* __restrict__ emb,
                        float* __restrict__ h0, int N,
                        const float* __restrict__ W1, float* __restrict__ W1p,
                        int countBlocks, int h0Blocks) {
    int b = blockIdx.x;
    if (b < countBlocks) {
        int e = b * 256 + threadIdx.x;
        if (e < E) atomicAdd(cnt + col[e], 1);
        return;
    }
    b -= countBlocks;
    if (b < h0Blocks) {
        int idx = b * 256 + threadIdx.x;
        if (idx >= N * 128) return;
        int i = idx >> 7;
        int k = idx & 127;
        const float* xr = x + (long)i * 5;
        float v;
        if (k < 62)       v = emb[(long)((int)xr[0]) * 62 + k];
        else if (k < 124) v = emb[(long)((int)xr[1]) * 62 + (k - 62)];
        else if (k < 127) v = xr[2 + (k - 124)];
        else              v = 0.f;
        h0[idx] = v;
        return;
    }
    b -= h0Blocks;
    {   // W1 pad: 128x64, row 127 = 0
        int idx = b * 256 + threadIdx.x;
        if (idx >= 128 * 64) return;
        int k = idx >> 6;
        W1p[idx] = (k < 127) ? W1[idx] : 0.f;
    }
}

// ---------------- multi-block scan ----------------
__global__ void k_scanA(const int* __restrict__ cnt, int* __restrict__ bsum,
                        int N, int chunk) {
    __shared__ int red[256];
    int t = threadIdx.x, b = blockIdx.x;
    int i = b * chunk + t;
    red[t] = (t < chunk && i < N) ? cnt[i] : 0;
    __syncthreads();
    for (int s = 128; s > 0; s >>= 1) {
        if (t < s) red[t] += red[t + s];
        __syncthreads();
    }
    if (t == 0) bsum[b] = red[0];
}

__global__ void k_scanB(const int* __restrict__ bsum, int* __restrict__ bloff,
                        int* __restrict__ gcur, int* __restrict__ off, int N) {
    __shared__ int sc[NBLK];
    int t = threadIdx.x;
    int v = bsum[t];
    sc[t] = v;
    __syncthreads();
    for (int d = 1; d < NBLK; d <<= 1) {
        int u = (t >= d) ? sc[t - d] : 0;
        __syncthreads();
        sc[t] += u;
        __syncthreads();
    }
    int excl = sc[t] - v;
    bloff[t] = excl;
    if ((t & 3) == 0) gcur[t >> 2] = excl;   // bucket b starts at chunk 4b
    if (t == NBLK - 1) off[N] = sc[t];       // == E
}

__global__ void k_scanC(const int* __restrict__ cnt, const int* __restrict__ bloff,
                        int* __restrict__ off, int* __restrict__ cursor,
                        float* __restrict__ dinv, int N, int chunk) {
    __shared__ int sc[256];
    int t = threadIdx.x, b = blockIdx.x;
    int i = b * chunk + t;
    int v = (t < chunk && i < N) ? cnt[i] : 0;
    sc[t] = v;
    __syncthreads();
    for (int d = 1; d < 256; d <<= 1) {
        int u = (t >= d) ? sc[t - d] : 0;
        __syncthreads();
        sc[t] += u;
        __syncthreads();
    }
    if (t < chunk && i < N) {
        int o = bloff[b] + sc[t] - v;
        off[i] = o;
        cursor[i] = o;
        dinv[i] = (float)(1.0 / sqrt((double)v + 1.0));
    }
}

// ---------------- bucket-sort edges, then locality-friendly CSR fill ----------------
__global__ void k_bucket(const int* __restrict__ row, const int* __restrict__ col,
                         int* __restrict__ gcur, unsigned int* __restrict__ ebuf,
                         int E, int S) {
    __shared__ int hist[NB], base[NB], lcur[NB];
    int t = threadIdx.x;
    if (t < NB) { hist[t] = 0; lcur[t] = 0; }
    __syncthreads();
    int e0 = blockIdx.x * BCHUNK;
    int e1 = min(e0 + BCHUNK, E);
    for (int e = e0 + t; e < e1; e += blockDim.x)
        atomicAdd(&hist[col[e] / S], 1);
    __syncthreads();
    if (t < NB) base[t] = hist[t] ? atomicAdd(&gcur[t], hist[t]) : 0;
    __syncthreads();
    for (int e = e0 + t; e < e1; e += blockDim.x) {
        int c = col[e], r = row[e];
        int b = c / S;
        int p = base[b] + atomicAdd(&lcur[b], 1);
        ebuf[p] = ((unsigned)c << 16) | (unsigned)r;
    }
}

__global__ void k_fillb(const unsigned int* __restrict__ ebuf, int* __restrict__ cursor,
                        int* __restrict__ srcs, int E) {
    int i = blockIdx.x * blockDim.x + threadIdx.x;
    if (i >= E) return;
    unsigned p = ebuf[i];
    int c = (int)(p >> 16), r = (int)(p & 0xFFFFu);
    int pos = atomicAdd(cursor + c, 1);
    srcs[pos] = r;
}

// ---------------- dense hws = (h @ W) * dinv, 4 outputs/thread, all-float4 ----------
template<int DIN, int DOUT>
__global__ void k_hw_v4(const float* __restrict__ h, int ld, const float* __restrict__ W,
                        const float* __restrict__ dinv, float* __restrict__ hws, int N) {
    constexpr int Q = DOUT / 4;
    int tid = blockIdx.x * blockDim.x + threadIdx.x;
    if (tid >= N * Q) return;
    int i = tid / Q;
    int q = tid % Q;
    const float4* hr4 = (const float4*)(h + (long)i * ld);
    const float* wp = W + 4 * q;
    float4 acc = make_float4(0.f, 0.f, 0.f, 0.f);
#pragma unroll 2
    for (int kk = 0; kk < DIN / 4; ++kk) {
        float4 hv = hr4[kk];
        float4 w0 = *(const float4*)(wp + (long)(4 * kk)     * DOUT);
        float4 w1 = *(const float4*)(wp + (long)(4 * kk + 1) * DOUT);
        float4 w2 = *(const float4*)(wp + (long)(4 * kk + 2) * DOUT);
        float4 w3 = *(const float4*)(wp + (long)(4 * kk + 3) * DOUT);
        acc.x += hv.x * w0.x + hv.y * w1.x + hv.z * w2.x + hv.w * w3.x;
        acc.y += hv.x * w0.y + hv.y * w1.y + hv.z * w2.y + hv.w * w3.y;
        acc.z += hv.x * w0.z + hv.y * w1.z + hv.z * w2.z + hv.w * w3.z;
        acc.w += hv.x * w0.w + hv.y * w1.w + hv.z * w2.w + hv.w * w3.w;
    }
    float di = dinv[i];
    acc.x *= di; acc.y *= di; acc.z *= di; acc.w *= di;
    *(float4*)(hws + (long)i * DOUT + 4 * q) = acc;
}

__global__ void k_hw_d1(const float* __restrict__ h, const float* __restrict__ W,
                        const float* __restrict__ dinv, float* __restrict__ hws, int N) {
    int i = blockIdx.x * blockDim.x + threadIdx.x;
    if (i >= N) return;
    const float4* hr4 = (const float4*)(h + (long)i * 32);
    float acc = 0.f;
#pragma unroll
    for (int kk = 0; kk < 8; ++kk) {
        float4 hv = hr4[kk];
        acc += hv.x * W[4 * kk] + hv.y * W[4 * kk + 1]
             + hv.z * W[4 * kk + 2] + hv.w * W[4 * kk + 3];
    }
    hws[i] = acc * dinv[i];
}

// ---------------- gather: out[c] = act( dc * (hws[c] + sum_e hws[src]) + b ) --------
template<int DOUT>
__global__ void k_gather_v4(const int* __restrict__ off, const int* __restrict__ srcs,
                            const float* __restrict__ dinv, const float* __restrict__ hws,
                            const float* __restrict__ b, float* __restrict__ out,
                            int N, int mode) {
    constexpr int Q = DOUT / 4;
    int tid = blockIdx.x * blockDim.x + threadIdx.x;
    if (tid >= N * Q) return;
    int c = tid / Q;
    int q = tid % Q;
    int e0 = off[c], e1 = off[c + 1];
    float dc = dinv[c];
    float4 acc = *(const float4*)(hws + (long)c * DOUT + 4 * q);  // self term
    int e = e0;
    for (; e + 3 < e1; e += 4) {
        int r0 = srcs[e], r1 = srcs[e + 1], r2 = srcs[e + 2], r3 = srcs[e + 3];
        float4 v0 = *(const float4*)(hws + (long)r0 * DOUT + 4 * q);
        float4 v1 = *(const float4*)(hws + (long)r1 * DOUT + 4 * q);
        float4 v2 = *(const float4*)(hws + (long)r2 * DOUT + 4 * q);
        float4 v3 = *(const float4*)(hws + (long)r3 * DOUT + 4 * q);
        acc.x += (v0.x + v1.x) + (v2.x + v3.x);
        acc.y += (v0.y + v1.y) + (v2.y + v3.y);
        acc.z += (v0.z + v1.z) + (v2.z + v3.z);
        acc.w += (v0.w + v1.w) + (v2.w + v3.w);
    }
    for (; e < e1; ++e) {
        int r = srcs[e];
        float4 v = *(const float4*)(hws + (long)r * DOUT + 4 * q);
        acc.x += v.x; acc.y += v.y; acc.z += v.z; acc.w += v.w;
    }
    float4 bb = *(const float4*)(b + 4 * q);
    float t0 = acc.x * dc + bb.x, t1 = acc.y * dc + bb.y;
    float t2 = acc.z * dc + bb.z, t3 = acc.w * dc + bb.w;
    float4 res;
    if (mode == 0) {
        res.x = (t0 >= 0.f) ? t0 : SLOPE * t0;
        res.y = (t1 >= 0.f) ? t1 : SLOPE * t1;
        res.z = (t2 >= 0.f) ? t2 : SLOPE * t2;
        res.w = (t3 >= 0.f) ? t3 : SLOPE * t3;
    } else {
        res.x = (t0 >= 0.f) ? 2.f * t0 : (1.f + SLOPE) * t0;
        res.y = (t1 >= 0.f) ? 2.f * t1 : (1.f + SLOPE) * t1;
        res.z = (t2 >= 0.f) ? 2.f * t2 : (1.f + SLOPE) * t2;
        res.w = (t3 >= 0.f) ? 2.f * t3 : (1.f + SLOPE) * t3;
    }
    *(float4*)(out + (long)c * DOUT + 4 * q) = res;
}

__global__ void k_gather_d1(const int* __restrict__ off, const int* __restrict__ srcs,
                            const float* __restrict__ dinv, const float* __restrict__ hws,
                            const float* __restrict__ b, float* __restrict__ out, int N) {
    int c = blockIdx.x * blockDim.x + threadIdx.x;
    if (c >= N) return;
    int e0 = off[c], e1 = off[c + 1];
    float acc = hws[c];
    int e = e0;
    float a1 = 0.f, a2 = 0.f, a3 = 0.f;
    for (; e + 3 < e1; e += 4) {
        acc += hws[srcs[e]];
        a1  += hws[srcs[e + 1]];
        a2  += hws[srcs[e + 2]];
        a3  += hws[srcs[e + 3]];
    }
    for (; e < e1; ++e) acc += hws[srcs[e]];
    float t = (acc + a1 + a2 + a3) * dinv[c] + b[0];
    out[c] = (t >= 0.f) ? t : SLOPE * t;
}

// ---------------- FC head ----------------
__global__ void k_fc1a(const float* __restrict__ v, const float* __restrict__ Wf1,
                       double* __restrict__ part, int N, int chunk) {
    int j = threadIdx.x;
    int bl = blockIdx.x;
    int i0 = bl * chunk, i1 = min(i0 + chunk, N);
    double a0 = 0.0, a1 = 0.0, a2 = 0.0, a3 = 0.0;
    int i = i0;
    for (; i + 3 < i1; i += 4) {
        a0 += (double)v[i]     * (double)Wf1[(long)i * 128 + j];
        a1 += (double)v[i + 1] * (double)Wf1[(long)(i + 1) * 128 + j];
        a2 += (double)v[i + 2] * (double)Wf1[(long)(i + 2) * 128 + j];
        a3 += (double)v[i + 3] * (double)Wf1[(long)(i + 3) * 128 + j];
    }
    for (; i < i1; ++i)
        a0 += (double)v[i] * (double)Wf1[(long)i * 128 + j];
    part[bl * 128 + j] = (a0 + a1) + (a2 + a3);
}

// o1[j] = relu( sum_bl part[bl,j] + bf1[j] ); one block per j, 256 threads
__global__ void k_fc1b(const double* __restrict__ part, const float* __restrict__ bf1,
                       float* __restrict__ o1) {
    __shared__ double red[256];
    int j = blockIdx.x;
    int t = threadIdx.x;
    double a = part[t * 128 + j] + part[(t + 256) * 128 + j];
    red[t] = a;
    __syncthreads();
    for (int s = 128; s > 0; s >>= 1) {
        if (t < s) red[t] += red[t + s];
        __syncthreads();
    }
    if (t == 0) {
        double v = red[0] + (double)bf1[j];
        o1[j] = (float)((v > 0.0) ? v : 0.0);
    }
}

// out[j] = relu( sum_k o1[k]*Wf2[k,j] + bf2[j] ); one block per j, 128 threads
__global__ void k_fc2(const float* __restrict__ o1, const float* __restrict__ Wf2,
                      const float* __restrict__ bf2, float* __restrict__ out) {
    __shared__ double red[128];
    int j = blockIdx.x;
    int k = threadIdx.x;
    red[k] = (double)o1[k] * (double)Wf2[(long)k * 128 + j];
    __syncthreads();
    for (int s = 64; s > 0; s >>= 1) {
        if (k < s) red[k] += red[k + s];
        __syncthreads();
    }
    if (k == 0) {
        double u = red[0] + (double)bf2[j];
        out[j] = (float)((u > 0.0) ? u : 0.0);
    }
}

// ---------------- layer driver ----------------
template<int DIN, int DOUT>
static void run_gcn(const float* hin, int ld, const float* W, const float* b, int mode,
                    const int* off, const int* srcs, const float* dinv,
                    float* HWS, float* hout, int N, hipStream_t stream) {
    constexpr int Q = DOUT / 4;
    k_hw_v4<DIN, DOUT><<<cdiv_l((long)N * Q, 256), 256, 0, stream>>>(hin, ld, W, dinv, HWS, N);
    k_gather_v4<DOUT><<<cdiv_l((long)N * Q, 256), 256, 0, stream>>>(
        off, srcs, dinv, HWS, b, hout, N, mode);
}

extern "C" void kernel_launch(void* const* d_in, const int* in_sizes, int n_in,
                              void* d_out, int out_size, void* d_ws, size_t ws_size,
                              hipStream_t stream) {
    const float* x   = (const float*)d_in[0];
    const int*   ei  = (const int*)d_in[1];
    const float* emb = (const float*)d_in[2];
    const float* W1  = (const float*)d_in[3];
    const float* b1  = (const float*)d_in[4];
    const float* W2  = (const float*)d_in[5];
    const float* b2  = (const float*)d_in[6];
    const float* W3  = (const float*)d_in[7];
    const float* b3  = (const float*)d_in[8];
    const float* W4  = (const float*)d_in[9];
    const float* b4  = (const float*)d_in[10];
    const float* W5  = (const float*)d_in[11];
    const float* b5  = (const float*)d_in[12];
    const float* Wf1 = (const float*)d_in[13];
    const float* bf1 = (const float*)d_in[14];
    const float* Wf2 = (const float*)d_in[15];
    const float* bf2 = (const float*)d_in[16];

    const int N = in_sizes[0] / 5;
    const int E = in_sizes[1] / 2;
    const int* row = ei;
    const int* col = ei + E;
    const int CHUNK = (N + NBLK - 1) / NBLK;
    const int S = 4 * CHUNK;

    // --- workspace carving ---
    char* ws = (char*)d_ws;
    size_t off_b = 0;
    auto alloc = [&](size_t bytes) -> void* {
        void* p = ws + off_b;
        off_b += (bytes + 255) & ~(size_t)255;
        return p;
    };
    int*   cnt    = (int*)alloc((size_t)N * sizeof(int));
    int*   offcsr = (int*)alloc((size_t)(N + 1) * sizeof(int));
    int*   cursor = (int*)alloc((size_t)N * sizeof(int));
    int*   bsum   = (int*)alloc((size_t)NBLK * sizeof(int));
    int*   bloff  = (int*)alloc((size_t)NBLK * sizeof(int));
    int*   gcur   = (int*)alloc((size_t)NB * sizeof(int));
    int*   srcs   = (int*)alloc((size_t)E * sizeof(int));
    unsigned int* ebuf = (unsigned int*)alloc((size_t)E * sizeof(unsigned int));
    float* dinv   = (float*)alloc((size_t)N * sizeof(float));
    float* W1p    = (float*)alloc((size_t)128 * 64 * sizeof(float));
    float* H0     = (float*)alloc((size_t)N * 128 * sizeof(float));
    float* HWS    = (float*)alloc((size_t)N * 64 * sizeof(float));
    float* HA     = (float*)alloc((size_t)N * 64 * sizeof(float));
    float* HB     = (float*)alloc((size_t)N * 64 * sizeof(float));
    float* V      = (float*)alloc((size_t)N * sizeof(float));
    double* part  = (double*)alloc((size_t)FC1_BLOCKS * 128 * sizeof(double));
    float* O1     = (float*)alloc(128 * sizeof(float));

    // --- front ---
    hipMemsetAsync(cnt, 0, (size_t)N * sizeof(int), stream);
    int countBlocks = cdiv_l(E, 256);
    int h0Blocks    = cdiv_l((long)N * 128, 256);
    int padBlocks   = cdiv_l(128 * 64, 256);
    k_front<<<countBlocks + h0Blocks + padBlocks, 256, 0, stream>>>(
        col, cnt, E, x, emb, H0, N, W1, W1p, countBlocks, h0Blocks);

    // --- scan + CSR ---
    k_scanA<<<NBLK, 256, 0, stream>>>(cnt, bsum, N, CHUNK);
    k_scanB<<<1, NBLK, 0, stream>>>(bsum, bloff, gcur, offcsr, N);
    k_scanC<<<NBLK, 256, 0, stream>>>(cnt, bloff, offcsr, cursor, dinv, N, CHUNK);
    k_bucket<<<cdiv_l(E, BCHUNK), 256, 0, stream>>>(row, col, gcur, ebuf, E, S);
    k_fillb<<<cdiv_l(E, 256), 256, 0, stream>>>(ebuf, cursor, srcs, E);

    // --- 5 GCN layers ---
    run_gcn<128, 64>(H0, 128, W1p, b1, 0, offcsr, srcs, dinv, HWS, HB, N, stream);
    run_gcn< 64, 32>(HB,  64, W2,  b2, 0, offcsr, srcs, dinv, HWS, HA, N, stream);
    run_gcn< 32, 32>(HA,  32, W3,  b3, 1, offcsr, srcs, dinv, HWS, HB, N, stream);
    run_gcn< 32, 32>(HB,  32, W4,  b4, 1, offcsr, srcs, dinv, HWS, HA, N, stream);
    k_hw_d1<<<cdiv_l(N, 256), 256, 0, stream>>>(HA, W5, dinv, HWS, N);
    k_gather_d1<<<cdiv_l(N, 256), 256, 0, stream>>>(offcsr, srcs, dinv, HWS, b5, V, N);

    // --- FC head ---
    int chunk = (N + FC1_BLOCKS - 1) / FC1_BLOCKS;
    k_fc1a<<<FC1_BLOCKS, 128, 0, stream>>>(V, Wf1, part, N, chunk);
    k_fc1b<<<128, 256, 0, stream>>>(part, bf1, O1);
    k_fc2<<<128, 128, 0, stream>>>(O1, Wf2, bf2, (float*)d_out);
}

// Round 8
// 444.555 us; speedup vs baseline: 4.1261x; 1.0309x over previous
//
#include <hip/hip_runtime.h>
#include <math.h>

#define SLOPE 0.01f
#define FC1_BLOCKS 512
#define NBLK 256       // scan chunks
#define NB 64          // CSR buckets
#define HBLK 256       // histogram blocks in k_front
#define BCHUNK 2048    // edges per k_bucket block

// ---------------------------------------------------------------------------
// R1: scatter-atomics -> CSR gather (atomics wrote 613 MB/layer to HBM).
// R2: fc1a 64 -> 512 blocks (was 1.2% occupancy, latency-bound).
// R3: f64 -> f32 in GCN path; float4 register blocking.
// R4: bucket-sorted CSR fill (k_fill had 16x write amplification).
// R5: multi-block scan; un-fused L1; hws = hw*dinv folded.
// R6: split single-block k_head (77us latency chain) into 128-block stages.
// R7: k_front's 1.2M random cnt-atomics wrote 37 MB to HBM (57 MB total,
//     66us). Remove them: k_front now does a 64-bin LDS bucket histogram
//     (16k atomics onto 64 ints); per-node counts come AFTER bucketing
//     (k_cnt2 on ebuf: each block's atomics hit one ~2.4 KB L2-resident
//     window). Bucket starts = scan of bucket counts == offcsr[b*S], so
//     ebuf/CSR region alignment is preserved exactly.
// ---------------------------------------------------------------------------

static inline int cdiv_l(long a, int b) { return (int)((a + (long)b - 1) / (long)b); }

// ---------------- merged front: bucket histogram | h0 build | W1 pad ----------------
__global__ void k_front(const int* __restrict__ col, int* __restrict__ bcnt, int E, int S,
                        const float* __restrict__ x, const float* __restrict__ emb,
                        float* __restrict__ h0, int N,
                        const float* __restrict__ W1, float* __restrict__ W1p,
                        int h0Blocks) {
    int b = blockIdx.x;
    if (b < HBLK) {
        __shared__ int hist[NB];
        int t = threadIdx.x;
        if (t < NB) hist[t] = 0;
        __syncthreads();
        for (int e = b * 256 + t; e < E; e += HBLK * 256)
            atomicAdd(&hist[col[e] / S], 1);
        __syncthreads();
        if (t < NB && hist[t]) atomicAdd(&bcnt[t], hist[t]);
        return;
    }
    b -= HBLK;
    if (b < h0Blocks) {
        int idx = b * 256 + threadIdx.x;
        if (idx >= N * 128) return;
        int i = idx >> 7;
        int k = idx & 127;
        const float* xr = x + (long)i * 5;
        float v;
        if (k < 62)       v = emb[(long)((int)xr[0]) * 62 + k];
        else if (k < 124) v = emb[(long)((int)xr[1]) * 62 + (k - 62)];
        else if (k < 127) v = xr[2 + (k - 124)];
        else              v = 0.f;
        h0[idx] = v;
        return;
    }
    b -= h0Blocks;
    {   // W1 pad: 128x64, row 127 = 0
        int idx = b * 256 + threadIdx.x;
        if (idx >= 128 * 64) return;
        int k = idx >> 6;
        W1p[idx] = (k < 127) ? W1[idx] : 0.f;
    }
}

// exclusive scan of 64 bucket counts -> gcur (bucket-region cursors)
__global__ void k_bscan(const int* __restrict__ bcnt, int* __restrict__ gcur) {
    __shared__ int sc[NB];
    int t = threadIdx.x;
    int v = bcnt[t];
    sc[t] = v;
    __syncthreads();
    for (int d = 1; d < NB; d <<= 1) {
        int u = (t >= d) ? sc[t - d] : 0;
        __syncthreads();
        sc[t] += u;
        __syncthreads();
    }
    gcur[t] = sc[t] - v;
}

// ---------------- bucket-sort edges ----------------
__global__ void k_bucket(const int* __restrict__ row, const int* __restrict__ col,
                         int* __restrict__ gcur, unsigned int* __restrict__ ebuf,
                         int E, int S) {
    __shared__ int hist[NB], base[NB], lcur[NB];
    int t = threadIdx.x;
    if (t < NB) { hist[t] = 0; lcur[t] = 0; }
    __syncthreads();
    int e0 = blockIdx.x * BCHUNK;
    int e1 = min(e0 + BCHUNK, E);
    for (int e = e0 + t; e < e1; e += blockDim.x)
        atomicAdd(&hist[col[e] / S], 1);
    __syncthreads();
    if (t < NB) base[t] = hist[t] ? atomicAdd(&gcur[t], hist[t]) : 0;
    __syncthreads();
    for (int e = e0 + t; e < e1; e += blockDim.x) {
        int c = col[e], r = row[e];
        int b = c / S;
        int p = base[b] + atomicAdd(&lcur[b], 1);
        ebuf[p] = ((unsigned)c << 16) | (unsigned)r;
    }
}

// per-node counts from bucketed ebuf: atomics land in small L2-resident windows
__global__ void k_cnt2(const unsigned int* __restrict__ ebuf, int* __restrict__ cnt, int E) {
    int i = blockIdx.x * blockDim.x + threadIdx.x;
    if (i < E) atomicAdd(cnt + (int)(ebuf[i] >> 16), 1);
}

// ---------------- multi-block scan ----------------
__global__ void k_scanA(const int* __restrict__ cnt, int* __restrict__ bsum,
                        int N, int chunk) {
    __shared__ int red[256];
    int t = threadIdx.x, b = blockIdx.x;
    int i = b * chunk + t;
    red[t] = (t < chunk && i < N) ? cnt[i] : 0;
    __syncthreads();
    for (int s = 128; s > 0; s >>= 1) {
        if (t < s) red[t] += red[t + s];
        __syncthreads();
    }
    if (t == 0) bsum[b] = red[0];
}

__global__ void k_scanB(const int* __restrict__ bsum, int* __restrict__ bloff,
                        int* __restrict__ off, int N) {
    __shared__ int sc[NBLK];
    int t = threadIdx.x;
    int v = bsum[t];
    sc[t] = v;
    __syncthreads();
    for (int d = 1; d < NBLK; d <<= 1) {
        int u = (t >= d) ? sc[t - d] : 0;
        __syncthreads();
        sc[t] += u;
        __syncthreads();
    }
    bloff[t] = sc[t] - v;
    if (t == NBLK - 1) off[N] = sc[t];   // == E
}

__global__ void k_scanC(const int* __restrict__ cnt, const int* __restrict__ bloff,
                        int* __restrict__ off, int* __restrict__ cursor,
                        float* __restrict__ dinv, int N, int chunk) {
    __shared__ int sc[256];
    int t = threadIdx.x, b = blockIdx.x;
    int i = b * chunk + t;
    int v = (t < chunk && i < N) ? cnt[i] : 0;
    sc[t] = v;
    __syncthreads();
    for (int d = 1; d < 256; d <<= 1) {
        int u = (t >= d) ? sc[t - d] : 0;
        __syncthreads();
        sc[t] += u;
        __syncthreads();
    }
    if (t < chunk && i < N) {
        int o = bloff[b] + sc[t] - v;
        off[i] = o;
        cursor[i] = o;
        dinv[i] = (float)(1.0 / sqrt((double)v + 1.0));
    }
}

__global__ void k_fillb(const unsigned int* __restrict__ ebuf, int* __restrict__ cursor,
                        int* __restrict__ srcs, int E) {
    int i = blockIdx.x * blockDim.x + threadIdx.x;
    if (i >= E) return;
    unsigned p = ebuf[i];
    int c = (int)(p >> 16), r = (int)(p & 0xFFFFu);
    int pos = atomicAdd(cursor + c, 1);
    srcs[pos] = r;
}

// ---------------- dense hws = (h @ W) * dinv, 4 outputs/thread, all-float4 ----------
template<int DIN, int DOUT>
__global__ void k_hw_v4(const float* __restrict__ h, int ld, const float* __restrict__ W,
                        const float* __restrict__ dinv, float* __restrict__ hws, int N) {
    constexpr int Q = DOUT / 4;
    int tid = blockIdx.x * blockDim.x + threadIdx.x;
    if (tid >= N * Q) return;
    int i = tid / Q;
    int q = tid % Q;
    const float4* hr4 = (const float4*)(h + (long)i * ld);
    const float* wp = W + 4 * q;
    float4 acc = make_float4(0.f, 0.f, 0.f, 0.f);
#pragma unroll 2
    for (int kk = 0; kk < DIN / 4; ++kk) {
        float4 hv = hr4[kk];
        float4 w0 = *(const float4*)(wp + (long)(4 * kk)     * DOUT);
        float4 w1 = *(const float4*)(wp + (long)(4 * kk + 1) * DOUT);
        float4 w2 = *(const float4*)(wp + (long)(4 * kk + 2) * DOUT);
        float4 w3 = *(const float4*)(wp + (long)(4 * kk + 3) * DOUT);
        acc.x += hv.x * w0.x + hv.y * w1.x + hv.z * w2.x + hv.w * w3.x;
        acc.y += hv.x * w0.y + hv.y * w1.y + hv.z * w2.y + hv.w * w3.y;
        acc.z += hv.x * w0.z + hv.y * w1.z + hv.z * w2.z + hv.w * w3.z;
        acc.w += hv.x * w0.w + hv.y * w1.w + hv.z * w2.w + hv.w * w3.w;
    }
    float di = dinv[i];
    acc.x *= di; acc.y *= di; acc.z *= di; acc.w *= di;
    *(float4*)(hws + (long)i * DOUT + 4 * q) = acc;
}

__global__ void k_hw_d1(const float* __restrict__ h, const float* __restrict__ W,
                        const float* __restrict__ dinv, float* __restrict__ hws, int N) {
    int i = blockIdx.x * blockDim.x + threadIdx.x;
    if (i >= N) return;
    const float4* hr4 = (const float4*)(h + (long)i * 32);
    float acc = 0.f;
#pragma unroll
    for (int kk = 0; kk < 8; ++kk) {
        float4 hv = hr4[kk];
        acc += hv.x * W[4 * kk] + hv.y * W[4 * kk + 1]
             + hv.z * W[4 * kk + 2] + hv.w * W[4 * kk + 3];
    }
    hws[i] = acc * dinv[i];
}

// ---------------- gather: out[c] = act( dc * (hws[c] + sum_e hws[src]) + b ) --------
template<int DOUT>
__global__ void k_gather_v4(const int* __restrict__ off, const int* __restrict__ srcs,
                            const float* __restrict__ dinv, const float* __restrict__ hws,
                            const float* __restrict__ b, float* __restrict__ out,
                            int N, int mode) {
    constexpr int Q = DOUT / 4;
    int tid = blockIdx.x * blockDim.x + threadIdx.x;
    if (tid >= N * Q) return;
    int c = tid / Q;
    int q = tid % Q;
    int e0 = off[c], e1 = off[c + 1];
    float dc = dinv[c];
    float4 acc = *(const float4*)(hws + (long)c * DOUT + 4 * q);  // self term
    int e = e0;
    for (; e + 3 < e1; e += 4) {
        int r0 = srcs[e], r1 = srcs[e + 1], r2 = srcs[e + 2], r3 = srcs[e + 3];
        float4 v0 = *(const float4*)(hws + (long)r0 * DOUT + 4 * q);
        float4 v1 = *(const float4*)(hws + (long)r1 * DOUT + 4 * q);
        float4 v2 = *(const float4*)(hws + (long)r2 * DOUT + 4 * q);
        float4 v3 = *(const float4*)(hws + (long)r3 * DOUT + 4 * q);
        acc.x += (v0.x + v1.x) + (v2.x + v3.x);
        acc.y += (v0.y + v1.y) + (v2.y + v3.y);
        acc.z += (v0.z + v1.z) + (v2.z + v3.z);
        acc.w += (v0.w + v1.w) + (v2.w + v3.w);
    }
    for (; e < e1; ++e) {
        int r = srcs[e];
        float4 v = *(const float4*)(hws + (long)r * DOUT + 4 * q);
        acc.x += v.x; acc.y += v.y; acc.z += v.z; acc.w += v.w;
    }
    float4 bb = *(const float4*)(b + 4 * q);
    float t0 = acc.x * dc + bb.x, t1 = acc.y * dc + bb.y;
    float t2 = acc.z * dc + bb.z, t3 = acc.w * dc + bb.w;
    float4 res;
    if (mode == 0) {
        res.x = (t0 >= 0.f) ? t0 : SLOPE * t0;
        res.y = (t1 >= 0.f) ? t1 : SLOPE * t1;
        res.z = (t2 >= 0.f) ? t2 : SLOPE * t2;
        res.w = (t3 >= 0.f) ? t3 : SLOPE * t3;
    } else {
        res.x = (t0 >= 0.f) ? 2.f * t0 : (1.f + SLOPE) * t0;
        res.y = (t1 >= 0.f) ? 2.f * t1 : (1.f + SLOPE) * t1;
        res.z = (t2 >= 0.f) ? 2.f * t2 : (1.f + SLOPE) * t2;
        res.w = (t3 >= 0.f) ? 2.f * t3 : (1.f + SLOPE) * t3;
    }
    *(float4*)(out + (long)c * DOUT + 4 * q) = res;
}

__global__ void k_gather_d1(const int* __restrict__ off, const int* __restrict__ srcs,
                            const float* __restrict__ dinv, const float* __restrict__ hws,
                            const float* __restrict__ b, float* __restrict__ out, int N) {
    int c = blockIdx.x * blockDim.x + threadIdx.x;
    if (c >= N) return;
    int e0 = off[c], e1 = off[c + 1];
    float acc = hws[c];
    int e = e0;
    float a1 = 0.f, a2 = 0.f, a3 = 0.f;
    for (; e + 3 < e1; e += 4) {
        acc += hws[srcs[e]];
        a1  += hws[srcs[e + 1]];
        a2  += hws[srcs[e + 2]];
        a3  += hws[srcs[e + 3]];
    }
    for (; e < e1; ++e) acc += hws[srcs[e]];
    float t = (acc + a1 + a2 + a3) * dinv[c] + b[0];
    out[c] = (t >= 0.f) ? t : SLOPE * t;
}

// ---------------- FC head ----------------
__global__ void k_fc1a(const float* __restrict__ v, const float* __restrict__ Wf1,
                       double* __restrict__ part, int N, int chunk) {
    int j = threadIdx.x;
    int bl = blockIdx.x;
    int i0 = bl * chunk, i1 = min(i0 + chunk, N);
    double a0 = 0.0, a1 = 0.0, a2 = 0.0, a3 = 0.0;
    int i = i0;
    for (; i + 3 < i1; i += 4) {
        a0 += (double)v[i]     * (double)Wf1[(long)i * 128 + j];
        a1 += (double)v[i + 1] * (double)Wf1[(long)(i + 1) * 128 + j];
        a2 += (double)v[i + 2] * (double)Wf1[(long)(i + 2) * 128 + j];
        a3 += (double)v[i + 3] * (double)Wf1[(long)(i + 3) * 128 + j];
    }
    for (; i < i1; ++i)
        a0 += (double)v[i] * (double)Wf1[(long)i * 128 + j];
    part[bl * 128 + j] = (a0 + a1) + (a2 + a3);
}

__global__ void k_fc1b(const double* __restrict__ part, const float* __restrict__ bf1,
                       float* __restrict__ o1) {
    __shared__ double red[256];
    int j = blockIdx.x;
    int t = threadIdx.x;
    double a = part[t * 128 + j] + part[(t + 256) * 128 + j];
    red[t] = a;
    __syncthreads();
    for (int s = 128; s > 0; s >>= 1) {
        if (t < s) red[t] += red[t + s];
        __syncthreads();
    }
    if (t == 0) {
        double v = red[0] + (double)bf1[j];
        o1[j] = (float)((v > 0.0) ? v : 0.0);
    }
}

__global__ void k_fc2(const float* __restrict__ o1, const float* __restrict__ Wf2,
                      const float* __restrict__ bf2, float* __restrict__ out) {
    __shared__ double red[128];
    int j = blockIdx.x;
    int k = threadIdx.x;
    red[k] = (double)o1[k] * (double)Wf2[(long)k * 128 + j];
    __syncthreads();
    for (int s = 64; s > 0; s >>= 1) {
        if (k < s) red[k] += red[k + s];
        __syncthreads();
    }
    if (k == 0) {
        double u = red[0] + (double)bf2[j];
        out[j] = (float)((u > 0.0) ? u : 0.0);
    }
}

// ---------------- layer driver ----------------
template<int DIN, int DOUT>
static void run_gcn(const float* hin, int ld, const float* W, const float* b, int mode,
                    const int* off, const int* srcs, const float* dinv,
                    float* HWS, float* hout, int N, hipStream_t stream) {
    constexpr int Q = DOUT / 4;
    k_hw_v4<DIN, DOUT><<<cdiv_l((long)N * Q, 256), 256, 0, stream>>>(hin, ld, W, dinv, HWS, N);
    k_gather_v4<DOUT><<<cdiv_l((long)N * Q, 256), 256, 0, stream>>>(
        off, srcs, dinv, HWS, b, hout, N, mode);
}

extern "C" void kernel_launch(void* const* d_in, const int* in_sizes, int n_in,
                              void* d_out, int out_size, void* d_ws, size_t ws_size,
                              hipStream_t stream) {
    const float* x   = (const float*)d_in[0];
    const int*   ei  = (const int*)d_in[1];
    const float* emb = (const float*)d_in[2];
    const float* W1  = (const float*)d_in[3];
    const float* b1  = (const float*)d_in[4];
    const float* W2  = (const float*)d_in[5];
    const float* b2  = (const float*)d_in[6];
    const float* W3  = (const float*)d_in[7];
    const float* b3  = (const float*)d_in[8];
    const float* W4  = (const float*)d_in[9];
    const float* b4  = (const float*)d_in[10];
    const float* W5  = (const float*)d_in[11];
    const float* b5  = (const float*)d_in[12];
    const float* Wf1 = (const float*)d_in[13];
    const float* bf1 = (const float*)d_in[14];
    const float* Wf2 = (const float*)d_in[15];
    const float* bf2 = (const float*)d_in[16];

    const int N = in_sizes[0] / 5;
    const int E = in_sizes[1] / 2;
    const int* row = ei;
    const int* col = ei + E;
    const int CHUNK = (N + NBLK - 1) / NBLK;   // scan chunk
    const int S = (N + NB - 1) / NB;           // bucket width

    // --- workspace carving ---
    char* ws = (char*)d_ws;
    size_t off_b = 0;
    auto alloc = [&](size_t bytes) -> void* {
        void* p = ws + off_b;
        off_b += (bytes + 255) & ~(size_t)255;
        return p;
    };
    int*   cnt    = (int*)alloc((size_t)N * sizeof(int));
    int*   offcsr = (int*)alloc((size_t)(N + 1) * sizeof(int));
    int*   cursor = (int*)alloc((size_t)N * sizeof(int));
    int*   bsum   = (int*)alloc((size_t)NBLK * sizeof(int));
    int*   bloff  = (int*)alloc((size_t)NBLK * sizeof(int));
    int*   bcnt   = (int*)alloc((size_t)NB * sizeof(int));
    int*   gcur   = (int*)alloc((size_t)NB * sizeof(int));
    int*   srcs   = (int*)alloc((size_t)E * sizeof(int));
    unsigned int* ebuf = (unsigned int*)alloc((size_t)E * sizeof(unsigned int));
    float* dinv   = (float*)alloc((size_t)N * sizeof(float));
    float* W1p    = (float*)alloc((size_t)128 * 64 * sizeof(float));
    float* H0     = (float*)alloc((size_t)N * 128 * sizeof(float));
    float* HWS    = (float*)alloc((size_t)N * 64 * sizeof(float));
    float* HA     = (float*)alloc((size_t)N * 64 * sizeof(float));
    float* HB     = (float*)alloc((size_t)N * 64 * sizeof(float));
    float* V      = (float*)alloc((size_t)N * sizeof(float));
    double* part  = (double*)alloc((size_t)FC1_BLOCKS * 128 * sizeof(double));
    float* O1     = (float*)alloc(128 * sizeof(float));

    // --- front: zero cnt+bcnt, merged (bucket-hist | h0 | W1pad) ---
    hipMemsetAsync(cnt, 0, (size_t)N * sizeof(int), stream);
    hipMemsetAsync(bcnt, 0, (size_t)NB * sizeof(int), stream);
    int h0Blocks  = cdiv_l((long)N * 128, 256);
    int padBlocks = cdiv_l(128 * 64, 256);
    k_front<<<HBLK + h0Blocks + padBlocks, 256, 0, stream>>>(
        col, bcnt, E, S, x, emb, H0, N, W1, W1p, h0Blocks);

    // --- CSR build ---
    k_bscan<<<1, NB, 0, stream>>>(bcnt, gcur);
    k_bucket<<<cdiv_l(E, BCHUNK), 256, 0, stream>>>(row, col, gcur, ebuf, E, S);
    k_cnt2<<<cdiv_l(E, 256), 256, 0, stream>>>(ebuf, cnt, E);
    k_scanA<<<NBLK, 256, 0, stream>>>(cnt, bsum, N, CHUNK);
    k_scanB<<<1, NBLK, 0, stream>>>(bsum, bloff, offcsr, N);
    k_scanC<<<NBLK, 256, 0, stream>>>(cnt, bloff, offcsr, cursor, dinv, N, CHUNK);
    k_fillb<<<cdiv_l(E, 256), 256, 0, stream>>>(ebuf, cursor, srcs, E);

    // --- 5 GCN layers ---
    run_gcn<128, 64>(H0, 128, W1p, b1, 0, offcsr, srcs, dinv, HWS, HB, N, stream);
    run_gcn< 64, 32>(HB,  64, W2,  b2, 0, offcsr, srcs, dinv, HWS, HA, N, stream);
    run_gcn< 32, 32>(HA,  32, W3,  b3, 1, offcsr, srcs, dinv, HWS, HB, N, stream);
    run_gcn< 32, 32>(HB,  32, W4,  b4, 1, offcsr, srcs, dinv, HWS, HA, N, stream);
    k_hw_d1<<<cdiv_l(N, 256), 256, 0, stream>>>(HA, W5, dinv, HWS, N);
    k_gather_d1<<<cdiv_l(N, 256), 256, 0, stream>>>(offcsr, srcs, dinv, HWS, b5, V, N);

    // --- FC head ---
    int chunk = (N + FC1_BLOCKS - 1) / FC1_BLOCKS;
    k_fc1a<<<FC1_BLOCKS, 128, 0, stream>>>(V, Wf1, part, N, chunk);
    k_fc1b<<<128, 256, 0, stream>>>(part, bf1, O1);
    k_fc2<<<128, 128, 0, stream>>>(O1, Wf2, bf2, (float*)d_out);
}

// Round 9
// 439.171 us; speedup vs baseline: 4.1767x; 1.0123x over previous
//
#include <hip/hip_runtime.h>
#include <math.h>

#define SLOPE 0.01f
#define FC1_BLOCKS 512
#define NBLK 256       // scan chunks
#define NB 64          // CSR buckets
#define HBLK 256       // histogram blocks in k_front
#define BCHUNK 2048    // edges per k_bucket block

// ---------------------------------------------------------------------------
// R1: scatter-atomics -> CSR gather (atomics wrote 613 MB/layer to HBM).
// R2: fc1a 64 -> 512 blocks (was 1.2% occupancy, latency-bound).
// R3: f64 -> f32 in GCN path; float4 register blocking.
// R4: bucket-sorted CSR fill (k_fill had 16x write amplification).
// R5: multi-block scan; un-fused L1; hws = hw*dinv folded.
// R6: split single-block k_head (77us latency chain) into 128-block stages.
// R7: bucket histogram instead of random cnt atomics (37 MB HBM writes).
// R8: k_hw_v4 was L1-BW bound: each thread privately re-read 2 KB of W ->
//     1.25 GB L1 traffic (50us, VALU 11%, HBM 400 GB/s). Now 4-node x
//     4-output register tiles: W chunk reused across 4 nodes (traffic /4),
//     16 lanes share h addresses (broadcast). FMA order per output
//     unchanged -> still bit-identical. Tail: h/dinv buffers over-allocated
//     +4 rows; only stores are guarded.
// ---------------------------------------------------------------------------

static inline int cdiv_l(long a, int b) { return (int)((a + (long)b - 1) / (long)b); }

// ---------------- merged front: bucket histogram | h0 build | W1 pad ----------------
__global__ void k_front(const int* __restrict__ col, int* __restrict__ bcnt, int E, int S,
                        const float* __restrict__ x, const float* __restrict__ emb,
                        float* __restrict__ h0, int N,
                        const float* __restrict__ W1, float* __restrict__ W1p,
                        int h0Blocks) {
    int b = blockIdx.x;
    if (b < HBLK) {
        __shared__ int hist[NB];
        int t = threadIdx.x;
        if (t < NB) hist[t] = 0;
        __syncthreads();
        for (int e = b * 256 + t; e < E; e += HBLK * 256)
            atomicAdd(&hist[col[e] / S], 1);
        __syncthreads();
        if (t < NB && hist[t]) atomicAdd(&bcnt[t], hist[t]);
        return;
    }
    b -= HBLK;
    if (b < h0Blocks) {
        int idx = b * 256 + threadIdx.x;
        if (idx >= N * 128) return;
        int i = idx >> 7;
        int k = idx & 127;
        const float* xr = x + (long)i * 5;
        float v;
        if (k < 62)       v = emb[(long)((int)xr[0]) * 62 + k];
        else if (k < 124) v = emb[(long)((int)xr[1]) * 62 + (k - 62)];
        else if (k < 127) v = xr[2 + (k - 124)];
        else              v = 0.f;
        h0[idx] = v;
        return;
    }
    b -= h0Blocks;
    {   // W1 pad: 128x64, row 127 = 0
        int idx = b * 256 + threadIdx.x;
        if (idx >= 128 * 64) return;
        int k = idx >> 6;
        W1p[idx] = (k < 127) ? W1[idx] : 0.f;
    }
}

// exclusive scan of 64 bucket counts -> gcur
__global__ void k_bscan(const int* __restrict__ bcnt, int* __restrict__ gcur) {
    __shared__ int sc[NB];
    int t = threadIdx.x;
    int v = bcnt[t];
    sc[t] = v;
    __syncthreads();
    for (int d = 1; d < NB; d <<= 1) {
        int u = (t >= d) ? sc[t - d] : 0;
        __syncthreads();
        sc[t] += u;
        __syncthreads();
    }
    gcur[t] = sc[t] - v;
}

// ---------------- bucket-sort edges ----------------
__global__ void k_bucket(const int* __restrict__ row, const int* __restrict__ col,
                         int* __restrict__ gcur, unsigned int* __restrict__ ebuf,
                         int E, int S) {
    __shared__ int hist[NB], base[NB], lcur[NB];
    int t = threadIdx.x;
    if (t < NB) { hist[t] = 0; lcur[t] = 0; }
    __syncthreads();
    int e0 = blockIdx.x * BCHUNK;
    int e1 = min(e0 + BCHUNK, E);
    for (int e = e0 + t; e < e1; e += blockDim.x)
        atomicAdd(&hist[col[e] / S], 1);
    __syncthreads();
    if (t < NB) base[t] = hist[t] ? atomicAdd(&gcur[t], hist[t]) : 0;
    __syncthreads();
    for (int e = e0 + t; e < e1; e += blockDim.x) {
        int c = col[e], r = row[e];
        int b = c / S;
        int p = base[b] + atomicAdd(&lcur[b], 1);
        ebuf[p] = ((unsigned)c << 16) | (unsigned)r;
    }
}

// per-node counts from bucketed ebuf (L2-resident windows)
__global__ void k_cnt2(const unsigned int* __restrict__ ebuf, int* __restrict__ cnt, int E) {
    int i = blockIdx.x * blockDim.x + threadIdx.x;
    if (i < E) atomicAdd(cnt + (int)(ebuf[i] >> 16), 1);
}

// ---------------- multi-block scan ----------------
__global__ void k_scanA(const int* __restrict__ cnt, int* __restrict__ bsum,
                        int N, int chunk) {
    __shared__ int red[256];
    int t = threadIdx.x, b = blockIdx.x;
    int i = b * chunk + t;
    red[t] = (t < chunk && i < N) ? cnt[i] : 0;
    __syncthreads();
    for (int s = 128; s > 0; s >>= 1) {
        if (t < s) red[t] += red[t + s];
        __syncthreads();
    }
    if (t == 0) bsum[b] = red[0];
}

__global__ void k_scanB(const int* __restrict__ bsum, int* __restrict__ bloff,
                        int* __restrict__ off, int N) {
    __shared__ int sc[NBLK];
    int t = threadIdx.x;
    int v = bsum[t];
    sc[t] = v;
    __syncthreads();
    for (int d = 1; d < NBLK; d <<= 1) {
        int u = (t >= d) ? sc[t - d] : 0;
        __syncthreads();
        sc[t] += u;
        __syncthreads();
    }
    bloff[t] = sc[t] - v;
    if (t == NBLK - 1) off[N] = sc[t];
}

__global__ void k_scanC(const int* __restrict__ cnt, const int* __restrict__ bloff,
                        int* __restrict__ off, int* __restrict__ cursor,
                        float* __restrict__ dinv, int N, int chunk) {
    __shared__ int sc[256];
    int t = threadIdx.x, b = blockIdx.x;
    int i = b * chunk + t;
    int v = (t < chunk && i < N) ? cnt[i] : 0;
    sc[t] = v;
    __syncthreads();
    for (int d = 1; d < 256; d <<= 1) {
        int u = (t >= d) ? sc[t - d] : 0;
        __syncthreads();
        sc[t] += u;
        __syncthreads();
    }
    if (t < chunk && i < N) {
        int o = bloff[b] + sc[t] - v;
        off[i] = o;
        cursor[i] = o;
        dinv[i] = (float)(1.0 / sqrt((double)v + 1.0));
    }
}

__global__ void k_fillb(const unsigned int* __restrict__ ebuf, int* __restrict__ cursor,
                        int* __restrict__ srcs, int E) {
    int i = blockIdx.x * blockDim.x + threadIdx.x;
    if (i >= E) return;
    unsigned p = ebuf[i];
    int c = (int)(p >> 16), r = (int)(p & 0xFFFFu);
    int pos = atomicAdd(cursor + c, 1);
    srcs[pos] = r;
}

// ---------------- dense hws = (h @ W) * dinv, 4-node x 4-output tiles ----------------
// thread -> (g = tid/Q: node group of 4, q = tid%Q: output group of 4).
// 16 consecutive lanes share g => h loads broadcast; W chunk reused across 4 nodes.
// h and dinv must be readable for 4*ceil(N/4) rows (over-allocated); stores guarded.
template<int DIN, int DOUT>
__global__ void k_hw_rb(const float* __restrict__ h, int ld, const float* __restrict__ W,
                        const float* __restrict__ dinv, float* __restrict__ hws, int N) {
    constexpr int Q = DOUT / 4;
    int tid = blockIdx.x * blockDim.x + threadIdx.x;
    int G = (N + 3) >> 2;
    if (tid >= G * Q) return;
    int g = tid / Q;
    int q = tid % Q;
    int i0 = 4 * g;
    const float4* h0 = (const float4*)(h + (long)i0 * ld);
    const float4* h1 = (const float4*)(h + (long)(i0 + 1) * ld);
    const float4* h2 = (const float4*)(h + (long)(i0 + 2) * ld);
    const float4* h3 = (const float4*)(h + (long)(i0 + 3) * ld);
    const float* wp = W + 4 * q;
    float4 acc0 = make_float4(0.f, 0.f, 0.f, 0.f);
    float4 acc1 = acc0, acc2 = acc0, acc3 = acc0;
#pragma unroll 4
    for (int kk = 0; kk < DIN / 4; ++kk) {
        float4 a0 = h0[kk], a1 = h1[kk], a2 = h2[kk], a3 = h3[kk];
        float4 w0 = *(const float4*)(wp + (long)(4 * kk)     * DOUT);
        float4 w1 = *(const float4*)(wp + (long)(4 * kk + 1) * DOUT);
        float4 w2 = *(const float4*)(wp + (long)(4 * kk + 2) * DOUT);
        float4 w3 = *(const float4*)(wp + (long)(4 * kk + 3) * DOUT);
        acc0.x += a0.x * w0.x + a0.y * w1.x + a0.z * w2.x + a0.w * w3.x;
        acc0.y += a0.x * w0.y + a0.y * w1.y + a0.z * w2.y + a0.w * w3.y;
        acc0.z += a0.x * w0.z + a0.y * w1.z + a0.z * w2.z + a0.w * w3.z;
        acc0.w += a0.x * w0.w + a0.y * w1.w + a0.z * w2.w + a0.w * w3.w;
        acc1.x += a1.x * w0.x + a1.y * w1.x + a1.z * w2.x + a1.w * w3.x;
        acc1.y += a1.x * w0.y + a1.y * w1.y + a1.z * w2.y + a1.w * w3.y;
        acc1.z += a1.x * w0.z + a1.y * w1.z + a1.z * w2.z + a1.w * w3.z;
        acc1.w += a1.x * w0.w + a1.y * w1.w + a1.z * w2.w + a1.w * w3.w;
        acc2.x += a2.x * w0.x + a2.y * w1.x + a2.z * w2.x + a2.w * w3.x;
        acc2.y += a2.x * w0.y + a2.y * w1.y + a2.z * w2.y + a2.w * w3.y;
        acc2.z += a2.x * w0.z + a2.y * w1.z + a2.z * w2.z + a2.w * w3.z;
        acc2.w += a2.x * w0.w + a2.y * w1.w + a2.z * w2.w + a2.w * w3.w;
        acc3.x += a3.x * w0.x + a3.y * w1.x + a3.z * w2.x + a3.w * w3.x;
        acc3.y += a3.x * w0.y + a3.y * w1.y + a3.z * w2.y + a3.w * w3.y;
        acc3.z += a3.x * w0.z + a3.y * w1.z + a3.z * w2.z + a3.w * w3.z;
        acc3.w += a3.x * w0.w + a3.y * w1.w + a3.z * w2.w + a3.w * w3.w;
    }
    float d0 = dinv[i0], d1 = dinv[i0 + 1], d2 = dinv[i0 + 2], d3 = dinv[i0 + 3];
    acc0.x *= d0; acc0.y *= d0; acc0.z *= d0; acc0.w *= d0;
    acc1.x *= d1; acc1.y *= d1; acc1.z *= d1; acc1.w *= d1;
    acc2.x *= d2; acc2.y *= d2; acc2.z *= d2; acc2.w *= d2;
    acc3.x *= d3; acc3.y *= d3; acc3.z *= d3; acc3.w *= d3;
    float* op = hws + (long)i0 * DOUT + 4 * q;
    *(float4*)(op) = acc0;
    if (i0 + 1 < N) *(float4*)(op + DOUT)     = acc1;
    if (i0 + 2 < N) *(float4*)(op + 2 * DOUT) = acc2;
    if (i0 + 3 < N) *(float4*)(op + 3 * DOUT) = acc3;
}

__global__ void k_hw_d1(const float* __restrict__ h, const float* __restrict__ W,
                        const float* __restrict__ dinv, float* __restrict__ hws, int N) {
    int i = blockIdx.x * blockDim.x + threadIdx.x;
    if (i >= N) return;
    const float4* hr4 = (const float4*)(h + (long)i * 32);
    float acc = 0.f;
#pragma unroll
    for (int kk = 0; kk < 8; ++kk) {
        float4 hv = hr4[kk];
        acc += hv.x * W[4 * kk] + hv.y * W[4 * kk + 1]
             + hv.z * W[4 * kk + 2] + hv.w * W[4 * kk + 3];
    }
    hws[i] = acc * dinv[i];
}

// ---------------- gather: out[c] = act( dc * (hws[c] + sum_e hws[src]) + b ) --------
template<int DOUT>
__global__ void k_gather_v4(const int* __restrict__ off, const int* __restrict__ srcs,
                            const float* __restrict__ dinv, const float* __restrict__ hws,
                            const float* __restrict__ b, float* __restrict__ out,
                            int N, int mode) {
    constexpr int Q = DOUT / 4;
    int tid = blockIdx.x * blockDim.x + threadIdx.x;
    if (tid >= N * Q) return;
    int c = tid / Q;
    int q = tid % Q;
    int e0 = off[c], e1 = off[c + 1];
    float dc = dinv[c];
    float4 acc = *(const float4*)(hws + (long)c * DOUT + 4 * q);  // self term
    int e = e0;
    for (; e + 3 < e1; e += 4) {
        int r0 = srcs[e], r1 = srcs[e + 1], r2 = srcs[e + 2], r3 = srcs[e + 3];
        float4 v0 = *(const float4*)(hws + (long)r0 * DOUT + 4 * q);
        float4 v1 = *(const float4*)(hws + (long)r1 * DOUT + 4 * q);
        float4 v2 = *(const float4*)(hws + (long)r2 * DOUT + 4 * q);
        float4 v3 = *(const float4*)(hws + (long)r3 * DOUT + 4 * q);
        acc.x += (v0.x + v1.x) + (v2.x + v3.x);
        acc.y += (v0.y + v1.y) + (v2.y + v3.y);
        acc.z += (v0.z + v1.z) + (v2.z + v3.z);
        acc.w += (v0.w + v1.w) + (v2.w + v3.w);
    }
    for (; e < e1; ++e) {
        int r = srcs[e];
        float4 v = *(const float4*)(hws + (long)r * DOUT + 4 * q);
        acc.x += v.x; acc.y += v.y; acc.z += v.z; acc.w += v.w;
    }
    float4 bb = *(const float4*)(b + 4 * q);
    float t0 = acc.x * dc + bb.x, t1 = acc.y * dc + bb.y;
    float t2 = acc.z * dc + bb.z, t3 = acc.w * dc + bb.w;
    float4 res;
    if (mode == 0) {
        res.x = (t0 >= 0.f) ? t0 : SLOPE * t0;
        res.y = (t1 >= 0.f) ? t1 : SLOPE * t1;
        res.z = (t2 >= 0.f) ? t2 : SLOPE * t2;
        res.w = (t3 >= 0.f) ? t3 : SLOPE * t3;
    } else {
        res.x = (t0 >= 0.f) ? 2.f * t0 : (1.f + SLOPE) * t0;
        res.y = (t1 >= 0.f) ? 2.f * t1 : (1.f + SLOPE) * t1;
        res.z = (t2 >= 0.f) ? 2.f * t2 : (1.f + SLOPE) * t2;
        res.w = (t3 >= 0.f) ? 2.f * t3 : (1.f + SLOPE) * t3;
    }
    *(float4*)(out + (long)c * DOUT + 4 * q) = res;
}

__global__ void k_gather_d1(const int* __restrict__ off, const int* __restrict__ srcs,
                            const float* __restrict__ dinv, const float* __restrict__ hws,
                            const float* __restrict__ b, float* __restrict__ out, int N) {
    int c = blockIdx.x * blockDim.x + threadIdx.x;
    if (c >= N) return;
    int e0 = off[c], e1 = off[c + 1];
    float acc = hws[c];
    int e = e0;
    float a1 = 0.f, a2 = 0.f, a3 = 0.f;
    for (; e + 3 < e1; e += 4) {
        acc += hws[srcs[e]];
        a1  += hws[srcs[e + 1]];
        a2  += hws[srcs[e + 2]];
        a3  += hws[srcs[e + 3]];
    }
    for (; e < e1; ++e) acc += hws[srcs[e]];
    float t = (acc + a1 + a2 + a3) * dinv[c] + b[0];
    out[c] = (t >= 0.f) ? t : SLOPE * t;
}

// ---------------- FC head ----------------
__global__ void k_fc1a(const float* __restrict__ v, const float* __restrict__ Wf1,
                       double* __restrict__ part, int N, int chunk) {
    int j = threadIdx.x;
    int bl = blockIdx.x;
    int i0 = bl * chunk, i1 = min(i0 + chunk, N);
    double a0 = 0.0, a1 = 0.0, a2 = 0.0, a3 = 0.0;
    int i = i0;
    for (; i + 3 < i1; i += 4) {
        a0 += (double)v[i]     * (double)Wf1[(long)i * 128 + j];
        a1 += (double)v[i + 1] * (double)Wf1[(long)(i + 1) * 128 + j];
        a2 += (double)v[i + 2] * (double)Wf1[(long)(i + 2) * 128 + j];
        a3 += (double)v[i + 3] * (double)Wf1[(long)(i + 3) * 128 + j];
    }
    for (; i < i1; ++i)
        a0 += (double)v[i] * (double)Wf1[(long)i * 128 + j];
    part[bl * 128 + j] = (a0 + a1) + (a2 + a3);
}

__global__ void k_fc1b(const double* __restrict__ part, const float* __restrict__ bf1,
                       float* __restrict__ o1) {
    __shared__ double red[256];
    int j = blockIdx.x;
    int t = threadIdx.x;
    double a = part[t * 128 + j] + part[(t + 256) * 128 + j];
    red[t] = a;
    __syncthreads();
    for (int s = 128; s > 0; s >>= 1) {
        if (t < s) red[t] += red[t + s];
        __syncthreads();
    }
    if (t == 0) {
        double v = red[0] + (double)bf1[j];
        o1[j] = (float)((v > 0.0) ? v : 0.0);
    }
}

__global__ void k_fc2(const float* __restrict__ o1, const float* __restrict__ Wf2,
                      const float* __restrict__ bf2, float* __restrict__ out) {
    __shared__ double red[128];
    int j = blockIdx.x;
    int k = threadIdx.x;
    red[k] = (double)o1[k] * (double)Wf2[(long)k * 128 + j];
    __syncthreads();
    for (int s = 64; s > 0; s >>= 1) {
        if (k < s) red[k] += red[k + s];
        __syncthreads();
    }
    if (k == 0) {
        double u = red[0] + (double)bf2[j];
        out[j] = (float)((u > 0.0) ? u : 0.0);
    }
}

// ---------------- layer driver ----------------
template<int DIN, int DOUT>
static void run_gcn(const float* hin, int ld, const float* W, const float* b, int mode,
                    const int* off, const int* srcs, const float* dinv,
                    float* HWS, float* hout, int N, hipStream_t stream) {
    constexpr int Q = DOUT / 4;
    int G = (N + 3) / 4;
    k_hw_rb<DIN, DOUT><<<cdiv_l((long)G * Q, 256), 256, 0, stream>>>(hin, ld, W, dinv, HWS, N);
    k_gather_v4<DOUT><<<cdiv_l((long)N * Q, 256), 256, 0, stream>>>(
        off, srcs, dinv, HWS, b, hout, N, mode);
}

extern "C" void kernel_launch(void* const* d_in, const int* in_sizes, int n_in,
                              void* d_out, int out_size, void* d_ws, size_t ws_size,
                              hipStream_t stream) {
    const float* x   = (const float*)d_in[0];
    const int*   ei  = (const int*)d_in[1];
    const float* emb = (const float*)d_in[2];
    const float* W1  = (const float*)d_in[3];
    const float* b1  = (const float*)d_in[4];
    const float* W2  = (const float*)d_in[5];
    const float* b2  = (const float*)d_in[6];
    const float* W3  = (const float*)d_in[7];
    const float* b3  = (const float*)d_in[8];
    const float* W4  = (const float*)d_in[9];
    const float* b4  = (const float*)d_in[10];
    const float* W5  = (const float*)d_in[11];
    const float* b5  = (const float*)d_in[12];
    const float* Wf1 = (const float*)d_in[13];
    const float* bf1 = (const float*)d_in[14];
    const float* Wf2 = (const float*)d_in[15];
    const float* bf2 = (const float*)d_in[16];

    const int N = in_sizes[0] / 5;
    const int E = in_sizes[1] / 2;
    const int* row = ei;
    const int* col = ei + E;
    const int CHUNK = (N + NBLK - 1) / NBLK;   // scan chunk
    const int S = (N + NB - 1) / NB;           // bucket width
    const int Np = N + 4;                       // padded rows for 4-node tiles

    // --- workspace carving ---
    char* ws = (char*)d_ws;
    size_t off_b = 0;
    auto alloc = [&](size_t bytes) -> void* {
        void* p = ws + off_b;
        off_b += (bytes + 255) & ~(size_t)255;
        return p;
    };
    int*   cnt    = (int*)alloc((size_t)N * sizeof(int));
    int*   offcsr = (int*)alloc((size_t)(N + 1) * sizeof(int));
    int*   cursor = (int*)alloc((size_t)N * sizeof(int));
    int*   bsum   = (int*)alloc((size_t)NBLK * sizeof(int));
    int*   bloff  = (int*)alloc((size_t)NBLK * sizeof(int));
    int*   bcnt   = (int*)alloc((size_t)NB * sizeof(int));
    int*   gcur   = (int*)alloc((size_t)NB * sizeof(int));
    int*   srcs   = (int*)alloc((size_t)E * sizeof(int));
    unsigned int* ebuf = (unsigned int*)alloc((size_t)E * sizeof(unsigned int));
    float* dinv   = (float*)alloc((size_t)Np * sizeof(float));
    float* W1p    = (float*)alloc((size_t)128 * 64 * sizeof(float));
    float* H0     = (float*)alloc((size_t)Np * 128 * sizeof(float));
    float* HWS    = (float*)alloc((size_t)Np * 64 * sizeof(float));
    float* HA     = (float*)alloc((size_t)Np * 64 * sizeof(float));
    float* HB     = (float*)alloc((size_t)Np * 64 * sizeof(float));
    float* V      = (float*)alloc((size_t)Np * sizeof(float));
    double* part  = (double*)alloc((size_t)FC1_BLOCKS * 128 * sizeof(double));
    float* O1     = (float*)alloc(128 * sizeof(float));

    // --- front: zero cnt+bcnt, merged (bucket-hist | h0 | W1pad) ---
    hipMemsetAsync(cnt, 0, (size_t)N * sizeof(int), stream);
    hipMemsetAsync(bcnt, 0, (size_t)NB * sizeof(int), stream);
    int h0Blocks  = cdiv_l((long)N * 128, 256);
    int padBlocks = cdiv_l(128 * 64, 256);
    k_front<<<HBLK + h0Blocks + padBlocks, 256, 0, stream>>>(
        col, bcnt, E, S, x, emb, H0, N, W1, W1p, h0Blocks);

    // --- CSR build ---
    k_bscan<<<1, NB, 0, stream>>>(bcnt, gcur);
    k_bucket<<<cdiv_l(E, BCHUNK), 256, 0, stream>>>(row, col, gcur, ebuf, E, S);
    k_cnt2<<<cdiv_l(E, 256), 256, 0, stream>>>(ebuf, cnt, E);
    k_scanA<<<NBLK, 256, 0, stream>>>(cnt, bsum, N, CHUNK);
    k_scanB<<<1, NBLK, 0, stream>>>(bsum, bloff, offcsr, N);
    k_scanC<<<NBLK, 256, 0, stream>>>(cnt, bloff, offcsr, cursor, dinv, N, CHUNK);
    k_fillb<<<cdiv_l(E, 256), 256, 0, stream>>>(ebuf, cursor, srcs, E);

    // --- 5 GCN layers ---
    run_gcn<128, 64>(H0, 128, W1p, b1, 0, offcsr, srcs, dinv, HWS, HB, N, stream);
    run_gcn< 64, 32>(HB,  64, W2,  b2, 0, offcsr, srcs, dinv, HWS, HA, N, stream);
    run_gcn< 32, 32>(HA,  32, W3,  b3, 1, offcsr, srcs, dinv, HWS, HB, N, stream);
    run_gcn< 32, 32>(HB,  32, W4,  b4, 1, offcsr, srcs, dinv, HWS, HA, N, stream);
    k_hw_d1<<<cdiv_l(N, 256), 256, 0, stream>>>(HA, W5, dinv, HWS, N);
    k_gather_d1<<<cdiv_l(N, 256), 256, 0, stream>>>(offcsr, srcs, dinv, HWS, b5, V, N);

    // --- FC head ---
    int chunk = (N + FC1_BLOCKS - 1) / FC1_BLOCKS;
    k_fc1a<<<FC1_BLOCKS, 128, 0, stream>>>(V, Wf1, part, N, chunk);
    k_fc1b<<<128, 256, 0, stream>>>(part, bf1, O1);
    k_fc2<<<128, 128, 0, stream>>>(O1, Wf2, bf2, (float*)d_out);
}